// Round 1
// baseline (4989.831 us; speedup 1.0000x reference)
//
#include <hip/hip_runtime.h>
#include <math.h>

// Problem dims
#define B_   128
#define N_   128
#define T_   256
#define OBS_ 512
#define ACT_ 64
#define M_   16
#define H_   128

typedef __attribute__((ext_vector_type(8))) short bf16x8;
typedef __attribute__((ext_vector_type(4))) float f32x4;

__device__ __forceinline__ unsigned short f2bf(float x) {
    unsigned int u = __float_as_uint(x);
    u += 0x7fffu + ((u >> 16) & 1u);
    return (unsigned short)(u >> 16);
}

// ---------------------------------------------------------------------------
// prep: convert Wih to bf16, bias sums, zero sync flags
// ---------------------------------------------------------------------------
__global__ void prep_kernel(const float* __restrict__ Wf_ih, const float* __restrict__ Wb_ih,
                            const float* __restrict__ bf_ih, const float* __restrict__ bf_hh,
                            const float* __restrict__ bb_ih, const float* __restrict__ bb_hh,
                            unsigned short* __restrict__ wihbf, float* __restrict__ biasz,
                            int* __restrict__ syncb) {
    int i = blockIdx.x * 256 + threadIdx.x;   // grid 512*256 = 131072
    if (i < 131072) {
        wihbf[i]          = f2bf(Wf_ih[i]);
        wihbf[131072 + i] = f2bf(Wb_ih[i]);
    }
    if (i < 512) {
        biasz[i]       = bf_ih[i] + bf_hh[i];
        biasz[512 + i] = bb_ih[i] + bb_hh[i];
    }
    if (i < 32768) syncb[i] = 0;
}

// ---------------------------------------------------------------------------
// generic fp32 GEMM  C[M,N] = A[M,K] @ B[K,N] + bias ; flags: 1=relu_out 2=relu_A
// tiles 64x64, BK=16, 256 threads
// ---------------------------------------------------------------------------
__global__ __launch_bounds__(256) void gemm64(const float* __restrict__ A,
                                              const float* __restrict__ Bm,
                                              const float* __restrict__ bias,
                                              float* __restrict__ C,
                                              int M, int N, int K, int flags) {
    __shared__ float As[16][68];
    __shared__ float Bs[16][68];
    const int t = threadIdx.x;
    const int row0 = blockIdx.y * 64, col0 = blockIdx.x * 64;
    const int tm = t >> 4, tn = t & 15;
    float acc[4][4] = {};
    for (int k0 = 0; k0 < K; k0 += 16) {
        {
            int r = t >> 2, kq = (t & 3) * 4;
            float4 v = *(const float4*)(A + (size_t)(row0 + r) * K + k0 + kq);
            if (flags & 2) {
                v.x = fmaxf(v.x, 0.f); v.y = fmaxf(v.y, 0.f);
                v.z = fmaxf(v.z, 0.f); v.w = fmaxf(v.w, 0.f);
            }
            As[kq + 0][r] = v.x; As[kq + 1][r] = v.y;
            As[kq + 2][r] = v.z; As[kq + 3][r] = v.w;
        }
        {
            int kk = t >> 4, nq = (t & 15) * 4;
            float4 v = *(const float4*)(Bm + (size_t)(k0 + kk) * N + col0 + nq);
            *(float4*)&Bs[kk][nq] = v;
        }
        __syncthreads();
#pragma unroll
        for (int kk = 0; kk < 16; ++kk) {
            float a[4], b[4];
#pragma unroll
            for (int i = 0; i < 4; ++i) a[i] = As[kk][tm * 4 + i];
#pragma unroll
            for (int j = 0; j < 4; ++j) b[j] = Bs[kk][tn * 4 + j];
#pragma unroll
            for (int i = 0; i < 4; ++i)
#pragma unroll
                for (int j = 0; j < 4; ++j) acc[i][j] = fmaf(a[i], b[j], acc[i][j]);
        }
        __syncthreads();
    }
#pragma unroll
    for (int i = 0; i < 4; ++i) {
#pragma unroll
        for (int j = 0; j < 4; ++j) {
            int col = col0 + tn * 4 + j;
            float v = acc[i][j] + (bias ? bias[col] : 0.f);
            if (flags & 1) v = fmaxf(v, 0.f);
            C[(size_t)(row0 + tm * 4 + i) * N + col] = v;
        }
    }
}

// ---------------------------------------------------------------------------
// LayerNorm over 256, one wave per row. Optional relu, optional dup output.
// ---------------------------------------------------------------------------
__global__ __launch_bounds__(256) void ln256_kernel(const float* __restrict__ X,
                                                    float* __restrict__ Y,
                                                    float* __restrict__ Y2,
                                                    const float* __restrict__ gam,
                                                    const float* __restrict__ bet,
                                                    int relu) {
#pragma clang fp contract(off)
    int row = blockIdx.x * 4 + (threadIdx.x >> 6);
    int l = threadIdx.x & 63;
    float4 x = *(const float4*)(X + (size_t)row * 256 + l * 4);
    float s = x.x + x.y + x.z + x.w;
#pragma unroll
    for (int d = 1; d < 64; d <<= 1) s += __shfl_xor(s, d);
    float mu = s * (1.f / 256.f);
    float d0 = x.x - mu, d1 = x.y - mu, d2 = x.z - mu, d3 = x.w - mu;
    float ss = d0 * d0 + d1 * d1 + d2 * d2 + d3 * d3;
#pragma unroll
    for (int d = 1; d < 64; d <<= 1) ss += __shfl_xor(ss, d);
    float var = ss * (1.f / 256.f);
    float sd = sqrtf(var + 1e-5f);
    float4 y;
    y.x = (d0 / sd) * gam[l * 4 + 0] + bet[l * 4 + 0];
    y.y = (d1 / sd) * gam[l * 4 + 1] + bet[l * 4 + 1];
    y.z = (d2 / sd) * gam[l * 4 + 2] + bet[l * 4 + 2];
    y.w = (d3 / sd) * gam[l * 4 + 3] + bet[l * 4 + 3];
    if (relu) {
        y.x = fmaxf(y.x, 0.f); y.y = fmaxf(y.y, 0.f);
        y.z = fmaxf(y.z, 0.f); y.w = fmaxf(y.w, 0.f);
    }
    *(float4*)(Y + (size_t)row * 256 + l * 4) = y;
    if (Y2) *(float4*)(Y2 + (size_t)row * 256 + l * 4) = y;
}

// LayerNorm over 64 + tanh, one wave per row
__global__ __launch_bounds__(256) void ln64_tanh_kernel(const float* __restrict__ X,
                                                        float* __restrict__ Y,
                                                        const float* __restrict__ gam,
                                                        const float* __restrict__ bet) {
#pragma clang fp contract(off)
    int row = blockIdx.x * 4 + (threadIdx.x >> 6);
    int l = threadIdx.x & 63;
    float x = X[(size_t)row * 64 + l];
    float s = x;
#pragma unroll
    for (int d = 1; d < 64; d <<= 1) s += __shfl_xor(s, d);
    float mu = s * (1.f / 64.f);
    float dx = x - mu;
    float ss = dx * dx;
#pragma unroll
    for (int d = 1; d < 64; d <<= 1) ss += __shfl_xor(ss, d);
    float var = ss * (1.f / 64.f);
    float sd = sqrtf(var + 1e-5f);
    float y = tanhf((dx / sd) * gam[l] + bet[l]);
    Y[(size_t)row * 64 + l] = y;
}

// ---------------------------------------------------------------------------
// attention head: p = sigmoid(a2 @ Wa3 + ba3), flags = p > 0.4
// ---------------------------------------------------------------------------
__global__ __launch_bounds__(256) void attn_head_kernel(const float* __restrict__ a2,
                                                        const float* __restrict__ Wa3,
                                                        const float* __restrict__ ba3,
                                                        float* __restrict__ outP,
                                                        float* __restrict__ outInit,
                                                        int* __restrict__ flags) {
#pragma clang fp contract(off)
    int row = blockIdx.x * 4 + (threadIdx.x >> 6);
    int l = threadIdx.x & 63;
    float s = a2[(size_t)row * 128 + l] * Wa3[l] + a2[(size_t)row * 128 + 64 + l] * Wa3[64 + l];
#pragma unroll
    for (int d = 1; d < 64; d <<= 1) s += __shfl_xor(s, d);
    s += ba3[0];
    float p = 1.f / (1.f + expf(-s));
    if (l == 0) {
        outP[row] = p;
        int f = (p > 0.4f) ? 1 : 0;
        outInit[row] = f ? 1.f : 0.f;
        flags[row] = f;
    }
}

// ---------------------------------------------------------------------------
// batched dot: dot[b] = th_b @ th_b^T   (128x128, K=256); 2 blocks per batch
// ---------------------------------------------------------------------------
__global__ __launch_bounds__(256) void dot_kernel(const float* __restrict__ th,
                                                  float* __restrict__ dotm) {
    __shared__ float As[16][68];
    __shared__ float Bs[16][132];
    const int b = blockIdx.x >> 1, half = blockIdx.x & 1;
    const int t = threadIdx.x;
    const int tm = t >> 4, tn = t & 15;
    float acc[4][8] = {};
    const float* base = th + (size_t)b * 128 * 256;
    for (int k0 = 0; k0 < 256; k0 += 16) {
        {
            int r = t >> 2, kq = (t & 3) * 4;
            float4 v = *(const float4*)(base + (size_t)(half * 64 + r) * 256 + k0 + kq);
            As[kq + 0][r] = v.x; As[kq + 1][r] = v.y;
            As[kq + 2][r] = v.z; As[kq + 3][r] = v.w;
        }
        {
            int n = t >> 1, kq = (t & 1) * 8;
            const float* src = base + (size_t)n * 256 + k0 + kq;
            float4 v0 = *(const float4*)src;
            float4 v1 = *(const float4*)(src + 4);
            Bs[kq + 0][n] = v0.x; Bs[kq + 1][n] = v0.y;
            Bs[kq + 2][n] = v0.z; Bs[kq + 3][n] = v0.w;
            Bs[kq + 4][n] = v1.x; Bs[kq + 5][n] = v1.y;
            Bs[kq + 6][n] = v1.z; Bs[kq + 7][n] = v1.w;
        }
        __syncthreads();
#pragma unroll
        for (int kk = 0; kk < 16; ++kk) {
            float a[4], bb[8];
#pragma unroll
            for (int i = 0; i < 4; ++i) a[i] = As[kk][tm * 4 + i];
#pragma unroll
            for (int j = 0; j < 8; ++j) bb[j] = Bs[kk][tn * 8 + j];
#pragma unroll
            for (int i = 0; i < 4; ++i)
#pragma unroll
                for (int j = 0; j < 8; ++j) acc[i][j] = fmaf(a[i], bb[j], acc[i][j]);
        }
        __syncthreads();
    }
#pragma unroll
    for (int i = 0; i < 4; ++i)
#pragma unroll
        for (int j = 0; j < 8; ++j)
            dotm[(size_t)b * 16384 + (size_t)(half * 64 + tm * 4 + i) * 128 + tn * 8 + j] = acc[i][j];
}

__global__ void sq_kernel(const float* __restrict__ dotm, float* __restrict__ sq) {
    int i = blockIdx.x * 256 + threadIdx.x;   // 64 blocks
    int b = i >> 7, n = i & 127;
    sq[i] = dotm[(size_t)b * 16384 + (size_t)n * 129];
}

// ---------------------------------------------------------------------------
// top-16 smallest distances per row (ties -> lower index), write C + idx
// one wave per row
// ---------------------------------------------------------------------------
__global__ __launch_bounds__(256) void topk_kernel(const float* __restrict__ dotm,
                                                   const float* __restrict__ sq,
                                                   const int* __restrict__ flags,
                                                   float* __restrict__ outC,
                                                   int* __restrict__ idxb) {
#pragma clang fp contract(off)
    int row = blockIdx.x * 4 + (threadIdx.x >> 6);
    int l = threadIdx.x & 63;
    int b = row >> 7;
    const float* drow = dotm + (size_t)row * 128;
    float sqi = sq[row];
    float t0 = 2.f * drow[l];
    float v0 = sq[b * 128 + l] - t0; v0 = v0 + sqi;
    float t1 = 2.f * drow[64 + l];
    float v1 = sq[b * 128 + 64 + l] - t1; v1 = v1 + sqi;

    unsigned long long mlo = 0ull, mhi = 0ull;
#pragma unroll 1
    for (int n = 0; n < 16; ++n) {
        float bv = v0; int bi = l;
        if (v1 < bv) { bv = v1; bi = 64 + l; }
#pragma unroll
        for (int d = 1; d < 64; d <<= 1) {
            float ov = __shfl_xor(bv, d);
            int oi = __shfl_xor(bi, d);
            if (ov < bv || (ov == bv && oi < bi)) { bv = ov; bi = oi; }
        }
        if (bi < 64) mlo |= (1ull << bi); else mhi |= (1ull << (bi - 64));
        if (l == bi) v0 = __builtin_inff();
        if (64 + l == bi) v1 = __builtin_inff();
    }
    float fl = (flags[row] != 0) ? 1.f : 0.f;
    outC[(size_t)row * 128 + l]      = fl * (((mlo >> l) & 1ull) ? 1.f : 0.f);
    outC[(size_t)row * 128 + 64 + l] = fl * (((mhi >> l) & 1ull) ? 1.f : 0.f);
    if (l < 16) {
        int cnt = 0, found = -1;
        for (int jj = 0; jj < 128; ++jj) {
            bool bit = (jj < 64) ? ((mlo >> jj) & 1ull) : ((mhi >> (jj - 64)) & 1ull);
            if (bit) { if (cnt == l) { found = jj; break; } ++cnt; }
        }
        idxb[(size_t)row * 16 + l] = found;
    }
}

// ---------------------------------------------------------------------------
// THE CHAIN: sequential per-agent bi-LSTM communication.
// 256 workgroups = (batch, dir); 512 threads; Whh held in VGPRs (fp32).
// thread t: j = t>>2 in [0,128) output index, q = t&3 k-quarter.
// Pair-synchronization via device-scope atomics (gather-done / scatter-done).
// ---------------------------------------------------------------------------
__global__ __launch_bounds__(512, 2) void chain_kernel(float* __restrict__ th,
                                                       const float* __restrict__ Whh_f,
                                                       const float* __restrict__ Whh_b,
                                                       const unsigned short* __restrict__ wihbf,
                                                       const float* __restrict__ biasz,
                                                       const int* __restrict__ idxb,
                                                       const int* __restrict__ flags,
                                                       int* __restrict__ syncb) {
    const int b = blockIdx.x >> 1, dir = blockIdx.x & 1;
    const int t = threadIdx.x;
    const int j = t >> 2, q = t & 3;
    const int w = t >> 6, l = t & 63, lr = l & 15, lg = l >> 4;

    __shared__ __align__(16) short grpb[4096];   // 16 x 256 bf16 (xor-swizzled rows)
    __shared__ float xg[16 * 516];               // per-member gate pre-activations
    __shared__ __align__(16) float hs[128];      // current hidden
    __shared__ int gis[16];

    // persistent recurrent weights: thread (j,q) holds rows {j,128+j,256+j,384+j}, k in [32q,32q+32)
    const float* Whh = dir ? Whh_b : Whh_f;
    float wreg[4][32];
#pragma unroll
    for (int gg = 0; gg < 4; ++gg) {
        const float* src = Whh + (size_t)(gg * 128 + j) * 128 + q * 32;
#pragma unroll
        for (int i = 0; i < 8; ++i) {
            float4 v = *(const float4*)(src + i * 4);
            wreg[gg][4 * i + 0] = v.x; wreg[gg][4 * i + 1] = v.y;
            wreg[gg][4 * i + 2] = v.z; wreg[gg][4 * i + 3] = v.w;
        }
    }
    const unsigned short* wih = wihbf + (size_t)dir * 131072;
    const float* bz = biasz + dir * 512;

    for (int ag = 0; ag < 128; ++ag) {
        if (!flags[b * 128 + ag]) continue;
        const int sidx = b * 128 + ag;
        if (t < 16) gis[t] = idxb[(size_t)sidx * 16 + t];
        __syncthreads();

        // gather group rows -> bf16 LDS (swizzled)
        {
            int m = t >> 5, c = t & 31;
            const float* src = th + (size_t)(b * 128 + gis[m]) * 256 + c * 8;
            float4 v0 = *(const float4*)src;
            float4 v1 = *(const float4*)(src + 4);
            bf16x8 sv;
            sv[0] = (short)f2bf(v0.x); sv[1] = (short)f2bf(v0.y);
            sv[2] = (short)f2bf(v0.z); sv[3] = (short)f2bf(v0.w);
            sv[4] = (short)f2bf(v1.x); sv[5] = (short)f2bf(v1.y);
            sv[6] = (short)f2bf(v1.z); sv[7] = (short)f2bf(v1.w);
            int byteoff = m * 512 + ((c * 16) ^ ((m & 7) << 4));
            *reinterpret_cast<bf16x8*>(reinterpret_cast<char*>(grpb) + byteoff) = sv;
        }
        __syncthreads();

        // sync A: both dirs finished reading pre-update rows
        if (t == 0) {
            __hip_atomic_fetch_add(&syncb[sidx], 1, __ATOMIC_RELEASE, __HIP_MEMORY_SCOPE_AGENT);
            unsigned int spins = 0;
            while (__hip_atomic_load(&syncb[sidx], __ATOMIC_ACQUIRE, __HIP_MEMORY_SCOPE_AGENT) < 2 &&
                   ++spins < 200000000u)
                __builtin_amdgcn_s_sleep(2);
        }
        __syncthreads();

        // xg = grp @ Wih^T + (bih + bhh), via bf16 MFMA (wave w owns gates [64w,64w+64))
        {
            f32x4 a0 = {0.f, 0.f, 0.f, 0.f}, a1 = a0, a2 = a0, a3 = a0;
#pragma unroll
            for (int kc = 0; kc < 8; ++kc) {
                int abyte = lr * 512 + ((kc * 64 + lg * 16) ^ ((lr & 7) << 4));
                bf16x8 af = *reinterpret_cast<const bf16x8*>(
                    reinterpret_cast<const char*>(grpb) + abyte);
                const unsigned short* wb = wih + (size_t)(w * 64 + lr) * 256 + kc * 32 + lg * 8;
                a0 = __builtin_amdgcn_mfma_f32_16x16x32_bf16(af, *(const bf16x8*)(wb),            a0, 0, 0, 0);
                a1 = __builtin_amdgcn_mfma_f32_16x16x32_bf16(af, *(const bf16x8*)(wb + 16 * 256), a1, 0, 0, 0);
                a2 = __builtin_amdgcn_mfma_f32_16x16x32_bf16(af, *(const bf16x8*)(wb + 32 * 256), a2, 0, 0, 0);
                a3 = __builtin_amdgcn_mfma_f32_16x16x32_bf16(af, *(const bf16x8*)(wb + 48 * 256), a3, 0, 0, 0);
            }
            int g0 = w * 64 + lr;
            float b0 = bz[g0], b1 = bz[g0 + 16], b2 = bz[g0 + 32], b3 = bz[g0 + 48];
#pragma unroll
            for (int r = 0; r < 4; ++r) {
                int m = lg * 4 + r;
                xg[m * 516 + g0]      = a0[r] + b0;
                xg[m * 516 + g0 + 16] = a1[r] + b1;
                xg[m * 516 + g0 + 32] = a2[r] + b2;
                xg[m * 516 + g0 + 48] = a3[r] + b3;
            }
        }
        if (t < 128) hs[t] = 0.f;
        __syncthreads();

        // 16-step recurrence (fwd: m=s ; bwd: m=15-s)
        float cst = 0.f;
        for (int s = 0; s < 16; ++s) {
            const int m = dir ? (15 - s) : s;
            float zi = 0.f, zf = 0.f, zg = 0.f, zo = 0.f;
#pragma unroll
            for (int kk = 0; kk < 8; ++kk) {
                const float4 hv = *reinterpret_cast<const float4*>(&hs[q * 32 + kk * 4]);
                const float hx0 = hv.x, hx1 = hv.y, hx2 = hv.z, hx3 = hv.w;
                zi = fmaf(wreg[0][kk * 4 + 0], hx0, zi); zi = fmaf(wreg[0][kk * 4 + 1], hx1, zi);
                zi = fmaf(wreg[0][kk * 4 + 2], hx2, zi); zi = fmaf(wreg[0][kk * 4 + 3], hx3, zi);
                zf = fmaf(wreg[1][kk * 4 + 0], hx0, zf); zf = fmaf(wreg[1][kk * 4 + 1], hx1, zf);
                zf = fmaf(wreg[1][kk * 4 + 2], hx2, zf); zf = fmaf(wreg[1][kk * 4 + 3], hx3, zf);
                zg = fmaf(wreg[2][kk * 4 + 0], hx0, zg); zg = fmaf(wreg[2][kk * 4 + 1], hx1, zg);
                zg = fmaf(wreg[2][kk * 4 + 2], hx2, zg); zg = fmaf(wreg[2][kk * 4 + 3], hx3, zg);
                zo = fmaf(wreg[3][kk * 4 + 0], hx0, zo); zo = fmaf(wreg[3][kk * 4 + 1], hx1, zo);
                zo = fmaf(wreg[3][kk * 4 + 2], hx2, zo); zo = fmaf(wreg[3][kk * 4 + 3], hx3, zo);
            }
            zi += __shfl_xor(zi, 1); zi += __shfl_xor(zi, 2);
            zf += __shfl_xor(zf, 1); zf += __shfl_xor(zf, 2);
            zg += __shfl_xor(zg, 1); zg += __shfl_xor(zg, 2);
            zo += __shfl_xor(zo, 1); zo += __shfl_xor(zo, 2);
            zi += xg[m * 516 + j];
            zf += xg[m * 516 + 128 + j];
            zg += xg[m * 516 + 256 + j];
            zo += xg[m * 516 + 384 + j];
            float ig = 1.f / (1.f + expf(-zi));
            float fg = 1.f / (1.f + expf(-zf));
            float gv = tanhf(zg);
            float og = 1.f / (1.f + expf(-zo));
            cst = fg * cst + ig * gv;
            float h = og * tanhf(cst);
            __syncthreads();   // all reads of hs done
            if (q == 0) {
                hs[j] = h;
                th[(size_t)(b * 128 + gis[m]) * 256 + dir * 128 + j] = h;
            }
            __syncthreads();   // hs update visible
        }

        // sync B: both dirs scattered -> next agent may gather
        if (t == 0) {
            __threadfence();
            __hip_atomic_fetch_add(&syncb[16384 + sidx], 1, __ATOMIC_RELEASE, __HIP_MEMORY_SCOPE_AGENT);
            unsigned int spins = 0;
            while (__hip_atomic_load(&syncb[16384 + sidx], __ATOMIC_ACQUIRE, __HIP_MEMORY_SCOPE_AGENT) < 2 &&
                   ++spins < 200000000u)
                __builtin_amdgcn_s_sleep(2);
            __threadfence();
        }
        __syncthreads();
    }
}

// ---------------------------------------------------------------------------
extern "C" void kernel_launch(void* const* d_in, const int* in_sizes, int n_in,
                              void* d_out, int out_size, void* d_ws, size_t ws_size,
                              hipStream_t stream) {
    const float* obs  = (const float*)d_in[0];
    const float* W1   = (const float*)d_in[1];
    const float* b1   = (const float*)d_in[2];
    const float* gg1  = (const float*)d_in[3];
    const float* be1  = (const float*)d_in[4];
    const float* W2   = (const float*)d_in[5];
    const float* b2   = (const float*)d_in[6];
    const float* gg2  = (const float*)d_in[7];
    const float* be2  = (const float*)d_in[8];
    const float* Wa1  = (const float*)d_in[9];
    const float* ba1  = (const float*)d_in[10];
    const float* Wa2  = (const float*)d_in[11];
    const float* ba2  = (const float*)d_in[12];
    const float* Wa3  = (const float*)d_in[13];
    const float* ba3  = (const float*)d_in[14];
    const float* Wf_ih = (const float*)d_in[15];
    const float* Wf_hh = (const float*)d_in[16];
    const float* bf_ih = (const float*)d_in[17];
    const float* bf_hh = (const float*)d_in[18];
    const float* Wb_ih = (const float*)d_in[19];
    const float* Wb_hh = (const float*)d_in[20];
    const float* bb_ih = (const float*)d_in[21];
    const float* bb_hh = (const float*)d_in[22];
    const float* W3   = (const float*)d_in[23];
    const float* b3   = (const float*)d_in[24];
    const float* gg3  = (const float*)d_in[25];
    const float* be3  = (const float*)d_in[26];
    const float* W4   = (const float*)d_in[27];
    const float* b4   = (const float*)d_in[28];
    const float* gg4  = (const float*)d_in[29];
    const float* be4  = (const float*)d_in[30];

    float* out     = (float*)d_out;
    float* out_acts = out;                   // 128*128*64
    float* out_C    = out + 1048576;         // 128*128*128
    float* out_ip   = out + 3145728;         // 16384
    float* out_ii   = out + 3162112;         // 16384
    float* out_nt   = out + 3178496;         // 128*128*256 (evolving thoughts)
    float* out_ot   = out + 7372800;         // 128*128*256 (old thoughts)

    float* ws    = (float*)d_ws;
    float* h1    = ws;                         // 4194304
    float* abuf  = ws + 4194304;               // 2097152 (a1, later dot)
    float* a2buf = ws + 6291456;               // 2097152 (a2, later act-pre)
    unsigned short* wihbf = (unsigned short*)(ws + 8388608);  // 262144 shorts
    float* biasz = ws + 8519680;               // 1024
    float* sqb   = ws + 8520704;               // 16384
    int* idxb    = (int*)(ws + 8537088);       // 262144
    int* flagsb  = (int*)(ws + 8799232);       // 16384
    int* syncb   = (int*)(ws + 8815616);       // 32768

    prep_kernel<<<512, 256, 0, stream>>>(Wf_ih, Wb_ih, bf_ih, bf_hh, bb_ih, bb_hh,
                                         wihbf, biasz, syncb);

    // actor_1
    gemm64<<<dim3(4, 256), 256, 0, stream>>>(obs, W1, b1, h1, 16384, 256, 512, 0);
    ln256_kernel<<<4096, 256, 0, stream>>>(h1, h1, nullptr, gg1, be1, 1);
    gemm64<<<dim3(4, 256), 256, 0, stream>>>(h1, W2, b2, out_nt, 16384, 256, 256, 0);
    ln256_kernel<<<4096, 256, 0, stream>>>(out_nt, out_nt, out_ot, gg2, be2, 0);

    // attention unit
    gemm64<<<dim3(2, 256), 256, 0, stream>>>(out_nt, Wa1, ba1, abuf, 16384, 128, 256, 1);
    gemm64<<<dim3(2, 256), 256, 0, stream>>>(abuf, Wa2, ba2, a2buf, 16384, 128, 128, 1);
    attn_head_kernel<<<4096, 256, 0, stream>>>(a2buf, Wa3, ba3, out_ip, out_ii, flagsb);

    // pairwise distances + top-16
    dot_kernel<<<256, 256, 0, stream>>>(out_nt, abuf);
    sq_kernel<<<64, 256, 0, stream>>>(abuf, sqb);
    topk_kernel<<<4096, 256, 0, stream>>>(abuf, sqb, flagsb, out_C, idxb);

    // sequential communication chain (mutates out_nt)
    chain_kernel<<<256, 512, 0, stream>>>(out_nt, Wf_hh, Wb_hh, wihbf, biasz,
                                          idxb, flagsb, syncb);

    // actor_2
    gemm64<<<dim3(4, 256), 256, 0, stream>>>(out_nt, W3, b3, h1, 16384, 256, 256, 2);
    ln256_kernel<<<4096, 256, 0, stream>>>(h1, h1, nullptr, gg3, be3, 0);
    gemm64<<<dim3(1, 256), 256, 0, stream>>>(h1, W4, b4, a2buf, 16384, 64, 256, 0);
    ln64_tanh_kernel<<<4096, 256, 0, stream>>>(a2buf, out_acts, gg4, be4);
}

// Round 2
// 4954.559 us; speedup vs baseline: 1.0071x; 1.0071x over previous
//
#include <hip/hip_runtime.h>
#include <math.h>

typedef __attribute__((ext_vector_type(8))) short bf16x8;
typedef __attribute__((ext_vector_type(4))) float f32x4;

__device__ __forceinline__ unsigned short f2bf(float x) {
    unsigned int u = __float_as_uint(x);
    u += 0x7fffu + ((u >> 16) & 1u);
    return (unsigned short)(u >> 16);
}
__device__ __forceinline__ float bf2f(unsigned short b) {
    return __uint_as_float(((unsigned int)b) << 16);
}

// ---------------------------------------------------------------------------
// prep: convert Wih and Whh to bf16, bias sums
// ---------------------------------------------------------------------------
__global__ void prep_kernel(const float* __restrict__ Wf_ih, const float* __restrict__ Wb_ih,
                            const float* __restrict__ Wf_hh, const float* __restrict__ Wb_hh,
                            const float* __restrict__ bf_ih, const float* __restrict__ bf_hh,
                            const float* __restrict__ bb_ih, const float* __restrict__ bb_hh,
                            unsigned short* __restrict__ wihbf,
                            unsigned short* __restrict__ whhbf,
                            float* __restrict__ biasz) {
    int i = blockIdx.x * 256 + threadIdx.x;   // grid 512*256 = 131072
    if (i < 131072) {
        wihbf[i]          = f2bf(Wf_ih[i]);
        wihbf[131072 + i] = f2bf(Wb_ih[i]);
    }
    if (i < 65536) {
        whhbf[i]         = f2bf(Wf_hh[i]);
        whhbf[65536 + i] = f2bf(Wb_hh[i]);
    }
    if (i < 512) {
        biasz[i]       = bf_ih[i] + bf_hh[i];
        biasz[512 + i] = bb_ih[i] + bb_hh[i];
    }
}

// ---------------------------------------------------------------------------
// generic fp32 GEMM  C[M,N] = A[M,K] @ B[K,N] + bias ; flags: 1=relu_out 2=relu_A
// ---------------------------------------------------------------------------
__global__ __launch_bounds__(256) void gemm64(const float* __restrict__ A,
                                              const float* __restrict__ Bm,
                                              const float* __restrict__ bias,
                                              float* __restrict__ C,
                                              int M, int N, int K, int flags) {
    __shared__ float As[16][68];
    __shared__ float Bs[16][68];
    const int t = threadIdx.x;
    const int row0 = blockIdx.y * 64, col0 = blockIdx.x * 64;
    const int tm = t >> 4, tn = t & 15;
    float acc[4][4] = {};
    for (int k0 = 0; k0 < K; k0 += 16) {
        {
            int r = t >> 2, kq = (t & 3) * 4;
            float4 v = *(const float4*)(A + (size_t)(row0 + r) * K + k0 + kq);
            if (flags & 2) {
                v.x = fmaxf(v.x, 0.f); v.y = fmaxf(v.y, 0.f);
                v.z = fmaxf(v.z, 0.f); v.w = fmaxf(v.w, 0.f);
            }
            As[kq + 0][r] = v.x; As[kq + 1][r] = v.y;
            As[kq + 2][r] = v.z; As[kq + 3][r] = v.w;
        }
        {
            int kk = t >> 4, nq = (t & 15) * 4;
            float4 v = *(const float4*)(Bm + (size_t)(k0 + kk) * N + col0 + nq);
            *(float4*)&Bs[kk][nq] = v;
        }
        __syncthreads();
#pragma unroll
        for (int kk = 0; kk < 16; ++kk) {
            float a[4], b[4];
#pragma unroll
            for (int i = 0; i < 4; ++i) a[i] = As[kk][tm * 4 + i];
#pragma unroll
            for (int j = 0; j < 4; ++j) b[j] = Bs[kk][tn * 4 + j];
#pragma unroll
            for (int i = 0; i < 4; ++i)
#pragma unroll
                for (int j = 0; j < 4; ++j) acc[i][j] = fmaf(a[i], b[j], acc[i][j]);
        }
        __syncthreads();
    }
#pragma unroll
    for (int i = 0; i < 4; ++i) {
#pragma unroll
        for (int j = 0; j < 4; ++j) {
            int col = col0 + tn * 4 + j;
            float v = acc[i][j] + (bias ? bias[col] : 0.f);
            if (flags & 1) v = fmaxf(v, 0.f);
            C[(size_t)(row0 + tm * 4 + i) * N + col] = v;
        }
    }
}

// ---------------------------------------------------------------------------
// LayerNorm over 256, one wave per row. Optional relu, optional dup output.
// ---------------------------------------------------------------------------
__global__ __launch_bounds__(256) void ln256_kernel(const float* __restrict__ X,
                                                    float* __restrict__ Y,
                                                    float* __restrict__ Y2,
                                                    const float* __restrict__ gam,
                                                    const float* __restrict__ bet,
                                                    int relu) {
#pragma clang fp contract(off)
    int row = blockIdx.x * 4 + (threadIdx.x >> 6);
    int l = threadIdx.x & 63;
    float4 x = *(const float4*)(X + (size_t)row * 256 + l * 4);
    float s = x.x + x.y + x.z + x.w;
#pragma unroll
    for (int d = 1; d < 64; d <<= 1) s += __shfl_xor(s, d);
    float mu = s * (1.f / 256.f);
    float d0 = x.x - mu, d1 = x.y - mu, d2 = x.z - mu, d3 = x.w - mu;
    float ss = d0 * d0 + d1 * d1 + d2 * d2 + d3 * d3;
#pragma unroll
    for (int d = 1; d < 64; d <<= 1) ss += __shfl_xor(ss, d);
    float var = ss * (1.f / 256.f);
    float sd = sqrtf(var + 1e-5f);
    float4 y;
    y.x = (d0 / sd) * gam[l * 4 + 0] + bet[l * 4 + 0];
    y.y = (d1 / sd) * gam[l * 4 + 1] + bet[l * 4 + 1];
    y.z = (d2 / sd) * gam[l * 4 + 2] + bet[l * 4 + 2];
    y.w = (d3 / sd) * gam[l * 4 + 3] + bet[l * 4 + 3];
    if (relu) {
        y.x = fmaxf(y.x, 0.f); y.y = fmaxf(y.y, 0.f);
        y.z = fmaxf(y.z, 0.f); y.w = fmaxf(y.w, 0.f);
    }
    *(float4*)(Y + (size_t)row * 256 + l * 4) = y;
    if (Y2) *(float4*)(Y2 + (size_t)row * 256 + l * 4) = y;
}

// LayerNorm over 64 + tanh, one wave per row
__global__ __launch_bounds__(256) void ln64_tanh_kernel(const float* __restrict__ X,
                                                        float* __restrict__ Y,
                                                        const float* __restrict__ gam,
                                                        const float* __restrict__ bet) {
#pragma clang fp contract(off)
    int row = blockIdx.x * 4 + (threadIdx.x >> 6);
    int l = threadIdx.x & 63;
    float x = X[(size_t)row * 64 + l];
    float s = x;
#pragma unroll
    for (int d = 1; d < 64; d <<= 1) s += __shfl_xor(s, d);
    float mu = s * (1.f / 64.f);
    float dx = x - mu;
    float ss = dx * dx;
#pragma unroll
    for (int d = 1; d < 64; d <<= 1) ss += __shfl_xor(ss, d);
    float var = ss * (1.f / 64.f);
    float sd = sqrtf(var + 1e-5f);
    float y = tanhf((dx / sd) * gam[l] + bet[l]);
    Y[(size_t)row * 64 + l] = y;
}

// ---------------------------------------------------------------------------
// attention head: p = sigmoid(a2 @ Wa3 + ba3), flags = p > 0.4
// ---------------------------------------------------------------------------
__global__ __launch_bounds__(256) void attn_head_kernel(const float* __restrict__ a2,
                                                        const float* __restrict__ Wa3,
                                                        const float* __restrict__ ba3,
                                                        float* __restrict__ outP,
                                                        float* __restrict__ outInit,
                                                        int* __restrict__ flags) {
#pragma clang fp contract(off)
    int row = blockIdx.x * 4 + (threadIdx.x >> 6);
    int l = threadIdx.x & 63;
    float s = a2[(size_t)row * 128 + l] * Wa3[l] + a2[(size_t)row * 128 + 64 + l] * Wa3[64 + l];
#pragma unroll
    for (int d = 1; d < 64; d <<= 1) s += __shfl_xor(s, d);
    s += ba3[0];
    float p = 1.f / (1.f + expf(-s));
    if (l == 0) {
        outP[row] = p;
        int f = (p > 0.4f) ? 1 : 0;
        outInit[row] = f ? 1.f : 0.f;
        flags[row] = f;
    }
}

// ---------------------------------------------------------------------------
// batched dot: dot[b] = th_b @ th_b^T   (128x128, K=256); 2 blocks per batch
// ---------------------------------------------------------------------------
__global__ __launch_bounds__(256) void dot_kernel(const float* __restrict__ th,
                                                  float* __restrict__ dotm) {
    __shared__ float As[16][68];
    __shared__ float Bs[16][132];
    const int b = blockIdx.x >> 1, half = blockIdx.x & 1;
    const int t = threadIdx.x;
    const int tm = t >> 4, tn = t & 15;
    float acc[4][8] = {};
    const float* base = th + (size_t)b * 128 * 256;
    for (int k0 = 0; k0 < 256; k0 += 16) {
        {
            int r = t >> 2, kq = (t & 3) * 4;
            float4 v = *(const float4*)(base + (size_t)(half * 64 + r) * 256 + k0 + kq);
            As[kq + 0][r] = v.x; As[kq + 1][r] = v.y;
            As[kq + 2][r] = v.z; As[kq + 3][r] = v.w;
        }
        {
            int n = t >> 1, kq = (t & 1) * 8;
            const float* src = base + (size_t)n * 256 + k0 + kq;
            float4 v0 = *(const float4*)src;
            float4 v1 = *(const float4*)(src + 4);
            Bs[kq + 0][n] = v0.x; Bs[kq + 1][n] = v0.y;
            Bs[kq + 2][n] = v0.z; Bs[kq + 3][n] = v0.w;
            Bs[kq + 4][n] = v1.x; Bs[kq + 5][n] = v1.y;
            Bs[kq + 6][n] = v1.z; Bs[kq + 7][n] = v1.w;
        }
        __syncthreads();
#pragma unroll
        for (int kk = 0; kk < 16; ++kk) {
            float a[4], bb[8];
#pragma unroll
            for (int i = 0; i < 4; ++i) a[i] = As[kk][tm * 4 + i];
#pragma unroll
            for (int j = 0; j < 8; ++j) bb[j] = Bs[kk][tn * 8 + j];
#pragma unroll
            for (int i = 0; i < 4; ++i)
#pragma unroll
                for (int j = 0; j < 8; ++j) acc[i][j] = fmaf(a[i], bb[j], acc[i][j]);
        }
        __syncthreads();
    }
#pragma unroll
    for (int i = 0; i < 4; ++i)
#pragma unroll
        for (int j = 0; j < 8; ++j)
            dotm[(size_t)b * 16384 + (size_t)(half * 64 + tm * 4 + i) * 128 + tn * 8 + j] = acc[i][j];
}

__global__ void sq_kernel(const float* __restrict__ dotm, float* __restrict__ sq) {
    int i = blockIdx.x * 256 + threadIdx.x;   // 64 blocks
    int b = i >> 7, n = i & 127;
    sq[i] = dotm[(size_t)b * 16384 + (size_t)n * 129];
}

// ---------------------------------------------------------------------------
// top-16 smallest distances per row (ties -> lower index), write C + idx
// ---------------------------------------------------------------------------
__global__ __launch_bounds__(256) void topk_kernel(const float* __restrict__ dotm,
                                                   const float* __restrict__ sq,
                                                   const int* __restrict__ flags,
                                                   float* __restrict__ outC,
                                                   int* __restrict__ idxb) {
#pragma clang fp contract(off)
    int row = blockIdx.x * 4 + (threadIdx.x >> 6);
    int l = threadIdx.x & 63;
    int b = row >> 7;
    const float* drow = dotm + (size_t)row * 128;
    float sqi = sq[row];
    float t0 = 2.f * drow[l];
    float v0 = sq[b * 128 + l] - t0; v0 = v0 + sqi;
    float t1 = 2.f * drow[64 + l];
    float v1 = sq[b * 128 + 64 + l] - t1; v1 = v1 + sqi;

    unsigned long long mlo = 0ull, mhi = 0ull;
#pragma unroll 1
    for (int n = 0; n < 16; ++n) {
        float bv = v0; int bi = l;
        if (v1 < bv) { bv = v1; bi = 64 + l; }
#pragma unroll
        for (int d = 1; d < 64; d <<= 1) {
            float ov = __shfl_xor(bv, d);
            int oi = __shfl_xor(bi, d);
            if (ov < bv || (ov == bv && oi < bi)) { bv = ov; bi = oi; }
        }
        if (bi < 64) mlo |= (1ull << bi); else mhi |= (1ull << (bi - 64));
        if (l == bi) v0 = __builtin_inff();
        if (64 + l == bi) v1 = __builtin_inff();
    }
    float fl = (flags[row] != 0) ? 1.f : 0.f;
    outC[(size_t)row * 128 + l]      = fl * (((mlo >> l) & 1ull) ? 1.f : 0.f);
    outC[(size_t)row * 128 + 64 + l] = fl * (((mhi >> l) & 1ull) ? 1.f : 0.f);
    if (l < 16) {
        int cnt = 0, found = -1;
        for (int jj = 0; jj < 128; ++jj) {
            bool bit = (jj < 64) ? ((mlo >> jj) & 1ull) : ((mhi >> (jj - 64)) & 1ull);
            if (bit) { if (cnt == l) { found = jj; break; } ++cnt; }
        }
        idxb[(size_t)row * 16 + l] = found;
    }
}

// ---------------------------------------------------------------------------
// THE CHAIN: one 512-thread block per batch, both LSTM dirs fused.
// waves 0-3: forward dir, waves 4-7: backward dir. Wave wd of a dir owns
// hidden units j in [32wd, 32wd+32): its 8 MFMA tiles are (gate-type G x
// half) so i,f,g,o of each j land IN-LANE -> no cross-lane cell update,
// ONE barrier per recurrence step. Whh bf16 fragments resident in VGPRs.
// ---------------------------------------------------------------------------
__global__ __launch_bounds__(512, 2) void chain_kernel(float* __restrict__ th,
                                                       const unsigned short* __restrict__ whhbf,
                                                       const unsigned short* __restrict__ wihbf,
                                                       const float* __restrict__ biasz,
                                                       const int* __restrict__ idxb,
                                                       const int* __restrict__ flags) {
    const int b = blockIdx.x;
    const int t = threadIdx.x;
    const int l = t & 63, lr = l & 15, lg = l >> 4;
    const int w = t >> 6, dir = w >> 2, wd = w & 3;

    __shared__ __align__(16) short grpb[4096];                 // 16x256 bf16, xor-swizzled rows
    __shared__ __align__(16) unsigned short xgs[2 * 16 * 520]; // per-(dir,member) gate pre-acts, bf16
    __shared__ __align__(16) unsigned short hbufs[2 * 256];    // ping-pong h (bf16), [p][dir][128]
    __shared__ int gis[16];

    // resident Whh bf16 B-fragments: wf[G][half][kc] -> gate G*128 + wd*32 + half*16 + lr
    bf16x8 wf[4][2][4];
    {
        const unsigned short* whh = whhbf + (size_t)dir * 65536;
#pragma unroll
        for (int G = 0; G < 4; ++G)
#pragma unroll
            for (int hf = 0; hf < 2; ++hf) {
                int gate = G * 128 + wd * 32 + hf * 16 + lr;
#pragma unroll
                for (int kc = 0; kc < 4; ++kc)
                    wf[G][hf][kc] = *(const bf16x8*)(whh + (size_t)gate * 128 + kc * 32 + lg * 8);
            }
    }
    const unsigned short* wih = wihbf + (size_t)dir * 131072;
    const float* bz = biasz + dir * 512;

    for (int ag = 0; ag < 128; ++ag) {
        if (!flags[b * 128 + ag]) continue;
        if (t < 16) gis[t] = idxb[(size_t)(b * 128 + ag) * 16 + t];
        __syncthreads();   // gis visible; previous agent's scatter drained

        // gather 16 group rows -> bf16 LDS (swizzled); zero h ping-buffer 0
        {
            int m = t >> 5, c = t & 31;
            const float* src = th + (size_t)(b * 128 + gis[m]) * 256 + c * 8;
            float4 v0 = *(const float4*)src;
            float4 v1 = *(const float4*)(src + 4);
            bf16x8 sv;
            sv[0] = (short)f2bf(v0.x); sv[1] = (short)f2bf(v0.y);
            sv[2] = (short)f2bf(v0.z); sv[3] = (short)f2bf(v0.w);
            sv[4] = (short)f2bf(v1.x); sv[5] = (short)f2bf(v1.y);
            sv[6] = (short)f2bf(v1.z); sv[7] = (short)f2bf(v1.w);
            int byteoff = m * 512 + ((c * 16) ^ ((m & 7) << 4));
            *reinterpret_cast<bf16x8*>(reinterpret_cast<char*>(grpb) + byteoff) = sv;
            if (t < 256) hbufs[t] = 0;
        }
        __syncthreads();   // grpb + hbuf0 ready

        // xg = grp @ Wih^T + (bih+bhh): wave owns 128 gates [wd*128, wd*128+128)
        {
            f32x4 xa[8];
#pragma unroll
            for (int ct = 0; ct < 8; ++ct) xa[ct] = (f32x4){0.f, 0.f, 0.f, 0.f};
#pragma unroll
            for (int kc = 0; kc < 8; ++kc) {
                int abyte = lr * 512 + ((kc * 64 + lg * 16) ^ ((lr & 7) << 4));
                bf16x8 af = *reinterpret_cast<const bf16x8*>(
                    reinterpret_cast<const char*>(grpb) + abyte);
#pragma unroll
                for (int ct = 0; ct < 8; ++ct) {
                    const unsigned short* wb =
                        wih + (size_t)(wd * 128 + ct * 16 + lr) * 256 + kc * 32 + lg * 8;
                    xa[ct] = __builtin_amdgcn_mfma_f32_16x16x32_bf16(
                        af, *(const bf16x8*)wb, xa[ct], 0, 0, 0);
                }
            }
#pragma unroll
            for (int ct = 0; ct < 8; ++ct) {
                int g = wd * 128 + ct * 16 + lr;
                float bb = bz[g];
#pragma unroll
                for (int r = 0; r < 4; ++r) {
                    int m = lg * 4 + r;
                    xgs[(dir * 16 + m) * 520 + g] = f2bf(xa[ct][r] + bb);
                }
            }
        }
        __syncthreads();   // xgs ready

        // 16-step recurrence; ONE barrier per step
        float cst0 = 0.f, cst1 = 0.f;
        for (int s = 0; s < 16; ++s) {
            const int m = dir ? (15 - s) : s;
            const int p = s & 1;
            f32x4 acc[8];
#pragma unroll
            for (int ct = 0; ct < 8; ++ct) acc[ct] = (f32x4){0.f, 0.f, 0.f, 0.f};
#pragma unroll
            for (int kc = 0; kc < 4; ++kc) {
                bf16x8 ha = *reinterpret_cast<const bf16x8*>(
                    &hbufs[p * 256 + dir * 128 + kc * 32 + lg * 8]);
#pragma unroll
                for (int G = 0; G < 4; ++G) {
                    acc[G * 2 + 0] = __builtin_amdgcn_mfma_f32_16x16x32_bf16(
                        ha, wf[G][0][kc], acc[G * 2 + 0], 0, 0, 0);
                    acc[G * 2 + 1] = __builtin_amdgcn_mfma_f32_16x16x32_bf16(
                        ha, wf[G][1][kc], acc[G * 2 + 1], 0, 0, 0);
                }
            }
            const unsigned short* xgm = &xgs[(dir * 16 + m) * 520];
            float* trow = th + (size_t)(b * 128 + gis[m]) * 256 + dir * 128;
#pragma unroll
            for (int hf = 0; hf < 2; ++hf) {
                int j = wd * 32 + hf * 16 + lr;
                float zi = acc[0 + hf][0] + bf2f(xgm[0 * 128 + j]);
                float zf = acc[2 + hf][0] + bf2f(xgm[1 * 128 + j]);
                float zg = acc[4 + hf][0] + bf2f(xgm[2 * 128 + j]);
                float zo = acc[6 + hf][0] + bf2f(xgm[3 * 128 + j]);
                float ig = 1.f / (1.f + expf(-zi));
                float fg = 1.f / (1.f + expf(-zf));
                float gv = tanhf(zg);
                float og = 1.f / (1.f + expf(-zo));
                float c_new = fg * (hf ? cst1 : cst0) + ig * gv;
                if (hf) cst1 = c_new; else cst0 = c_new;
                float h = og * tanhf(c_new);
                if (l < 16) {
                    hbufs[(p ^ 1) * 256 + dir * 128 + j] = f2bf(h);
                    trow[j] = h;
                }
            }
            __syncthreads();   // h(p^1) + scatter visible for next step/agent
        }
    }
}

// ---------------------------------------------------------------------------
extern "C" void kernel_launch(void* const* d_in, const int* in_sizes, int n_in,
                              void* d_out, int out_size, void* d_ws, size_t ws_size,
                              hipStream_t stream) {
    const float* obs  = (const float*)d_in[0];
    const float* W1   = (const float*)d_in[1];
    const float* b1   = (const float*)d_in[2];
    const float* gg1  = (const float*)d_in[3];
    const float* be1  = (const float*)d_in[4];
    const float* W2   = (const float*)d_in[5];
    const float* b2   = (const float*)d_in[6];
    const float* gg2  = (const float*)d_in[7];
    const float* be2  = (const float*)d_in[8];
    const float* Wa1  = (const float*)d_in[9];
    const float* ba1  = (const float*)d_in[10];
    const float* Wa2  = (const float*)d_in[11];
    const float* ba2  = (const float*)d_in[12];
    const float* Wa3  = (const float*)d_in[13];
    const float* ba3  = (const float*)d_in[14];
    const float* Wf_ih = (const float*)d_in[15];
    const float* Wf_hh = (const float*)d_in[16];
    const float* bf_ih = (const float*)d_in[17];
    const float* bf_hh = (const float*)d_in[18];
    const float* Wb_ih = (const float*)d_in[19];
    const float* Wb_hh = (const float*)d_in[20];
    const float* bb_ih = (const float*)d_in[21];
    const float* bb_hh = (const float*)d_in[22];
    const float* W3   = (const float*)d_in[23];
    const float* b3   = (const float*)d_in[24];
    const float* gg3  = (const float*)d_in[25];
    const float* be3  = (const float*)d_in[26];
    const float* W4   = (const float*)d_in[27];
    const float* b4   = (const float*)d_in[28];
    const float* gg4  = (const float*)d_in[29];
    const float* be4  = (const float*)d_in[30];

    float* out     = (float*)d_out;
    float* out_acts = out;                   // 128*128*64
    float* out_C    = out + 1048576;         // 128*128*128
    float* out_ip   = out + 3145728;         // 16384
    float* out_ii   = out + 3162112;         // 16384
    float* out_nt   = out + 3178496;         // 128*128*256 (evolving thoughts)
    float* out_ot   = out + 7372800;         // 128*128*256 (old thoughts)

    float* ws    = (float*)d_ws;
    float* h1    = ws;                               // 4194304
    float* abuf  = ws + 4194304;                     // 2097152 (a1, later dot)
    float* a2buf = ws + 6291456;                     // 2097152 (a2, later act-pre)
    unsigned short* wihbf = (unsigned short*)(ws + 8388608);  // 262144 shorts
    float* biasz = ws + 8519680;                     // 1024
    unsigned short* whhbf = (unsigned short*)(ws + 8520704);  // 131072 shorts
    float* sqb   = ws + 8586240;                     // 16384
    int* idxb    = (int*)(ws + 8602624);             // 262144
    int* flagsb  = (int*)(ws + 8864768);             // 16384

    prep_kernel<<<512, 256, 0, stream>>>(Wf_ih, Wb_ih, Wf_hh, Wb_hh,
                                         bf_ih, bf_hh, bb_ih, bb_hh,
                                         wihbf, whhbf, biasz);

    // actor_1
    gemm64<<<dim3(4, 256), 256, 0, stream>>>(obs, W1, b1, h1, 16384, 256, 512, 0);
    ln256_kernel<<<4096, 256, 0, stream>>>(h1, h1, nullptr, gg1, be1, 1);
    gemm64<<<dim3(4, 256), 256, 0, stream>>>(h1, W2, b2, out_nt, 16384, 256, 256, 0);
    ln256_kernel<<<4096, 256, 0, stream>>>(out_nt, out_nt, out_ot, gg2, be2, 0);

    // attention unit
    gemm64<<<dim3(2, 256), 256, 0, stream>>>(out_nt, Wa1, ba1, abuf, 16384, 128, 256, 1);
    gemm64<<<dim3(2, 256), 256, 0, stream>>>(abuf, Wa2, ba2, a2buf, 16384, 128, 128, 1);
    attn_head_kernel<<<4096, 256, 0, stream>>>(a2buf, Wa3, ba3, out_ip, out_ii, flagsb);

    // pairwise distances + top-16
    dot_kernel<<<256, 256, 0, stream>>>(out_nt, abuf);
    sq_kernel<<<64, 256, 0, stream>>>(abuf, sqb);
    topk_kernel<<<4096, 256, 0, stream>>>(abuf, sqb, flagsb, out_C, idxb);

    // sequential communication chain (mutates out_nt), both dirs fused per block
    chain_kernel<<<128, 512, 0, stream>>>(out_nt, whhbf, wihbf, biasz, idxb, flagsb);

    // actor_2
    gemm64<<<dim3(4, 256), 256, 0, stream>>>(out_nt, W3, b3, h1, 16384, 256, 256, 2);
    ln256_kernel<<<4096, 256, 0, stream>>>(h1, h1, nullptr, gg3, be3, 0);
    gemm64<<<dim3(1, 256), 256, 0, stream>>>(h1, W4, b4, a2buf, 16384, 64, 256, 0);
    ln64_tanh_kernel<<<4096, 256, 0, stream>>>(a2buf, out_acts, gg4, be4);
}

// Round 3
// 4694.797 us; speedup vs baseline: 1.0628x; 1.0553x over previous
//
#include <hip/hip_runtime.h>
#include <math.h>

typedef __attribute__((ext_vector_type(8))) short bf16x8;
typedef __attribute__((ext_vector_type(4))) float f32x4;

__device__ __forceinline__ unsigned short f2bf(float x) {
    unsigned int u = __float_as_uint(x);
    u += 0x7fffu + ((u >> 16) & 1u);
    return (unsigned short)(u >> 16);
}
__device__ __forceinline__ float bf2f(unsigned short b) {
    return __uint_as_float(((unsigned int)b) << 16);
}
// fast activations: v_exp_f32 + v_rcp_f32 (rel err ~1e-7, far below bf16 noise)
__device__ __forceinline__ float fsig(float z) {
    float e = __expf(-z);
    return __builtin_amdgcn_rcpf(1.f + e);
}
__device__ __forceinline__ float ftanh(float x) {
    float ax = fabsf(x);
    float e = __expf(-2.f * ax);
    float r = (1.f - e) * __builtin_amdgcn_rcpf(1.f + e);
    return copysignf(r, x);
}

// ---------------------------------------------------------------------------
// prep: convert Wih and Whh to bf16, bias sums
// ---------------------------------------------------------------------------
__global__ void prep_kernel(const float* __restrict__ Wf_ih, const float* __restrict__ Wb_ih,
                            const float* __restrict__ Wf_hh, const float* __restrict__ Wb_hh,
                            const float* __restrict__ bf_ih, const float* __restrict__ bf_hh,
                            const float* __restrict__ bb_ih, const float* __restrict__ bb_hh,
                            unsigned short* __restrict__ wihbf,
                            unsigned short* __restrict__ whhbf,
                            float* __restrict__ biasz) {
    int i = blockIdx.x * 256 + threadIdx.x;   // grid 512*256 = 131072
    if (i < 131072) {
        wihbf[i]          = f2bf(Wf_ih[i]);
        wihbf[131072 + i] = f2bf(Wb_ih[i]);
    }
    if (i < 65536) {
        whhbf[i]         = f2bf(Wf_hh[i]);
        whhbf[65536 + i] = f2bf(Wb_hh[i]);
    }
    if (i < 512) {
        biasz[i]       = bf_ih[i] + bf_hh[i];
        biasz[512 + i] = bb_ih[i] + bb_hh[i];
    }
}

// ---------------------------------------------------------------------------
// generic fp32 GEMM  C[M,N] = A[M,K] @ B[K,N] + bias ; flags: 1=relu_out 2=relu_A
// ---------------------------------------------------------------------------
__global__ __launch_bounds__(256) void gemm64(const float* __restrict__ A,
                                              const float* __restrict__ Bm,
                                              const float* __restrict__ bias,
                                              float* __restrict__ C,
                                              int M, int N, int K, int flags) {
    __shared__ float As[16][68];
    __shared__ float Bs[16][68];
    const int t = threadIdx.x;
    const int row0 = blockIdx.y * 64, col0 = blockIdx.x * 64;
    const int tm = t >> 4, tn = t & 15;
    float acc[4][4] = {};
    for (int k0 = 0; k0 < K; k0 += 16) {
        {
            int r = t >> 2, kq = (t & 3) * 4;
            float4 v = *(const float4*)(A + (size_t)(row0 + r) * K + k0 + kq);
            if (flags & 2) {
                v.x = fmaxf(v.x, 0.f); v.y = fmaxf(v.y, 0.f);
                v.z = fmaxf(v.z, 0.f); v.w = fmaxf(v.w, 0.f);
            }
            As[kq + 0][r] = v.x; As[kq + 1][r] = v.y;
            As[kq + 2][r] = v.z; As[kq + 3][r] = v.w;
        }
        {
            int kk = t >> 4, nq = (t & 15) * 4;
            float4 v = *(const float4*)(Bm + (size_t)(k0 + kk) * N + col0 + nq);
            *(float4*)&Bs[kk][nq] = v;
        }
        __syncthreads();
#pragma unroll
        for (int kk = 0; kk < 16; ++kk) {
            float a[4], b[4];
#pragma unroll
            for (int i = 0; i < 4; ++i) a[i] = As[kk][tm * 4 + i];
#pragma unroll
            for (int j = 0; j < 4; ++j) b[j] = Bs[kk][tn * 4 + j];
#pragma unroll
            for (int i = 0; i < 4; ++i)
#pragma unroll
                for (int j = 0; j < 4; ++j) acc[i][j] = fmaf(a[i], b[j], acc[i][j]);
        }
        __syncthreads();
    }
#pragma unroll
    for (int i = 0; i < 4; ++i) {
#pragma unroll
        for (int j = 0; j < 4; ++j) {
            int col = col0 + tn * 4 + j;
            float v = acc[i][j] + (bias ? bias[col] : 0.f);
            if (flags & 1) v = fmaxf(v, 0.f);
            C[(size_t)(row0 + tm * 4 + i) * N + col] = v;
        }
    }
}

// ---------------------------------------------------------------------------
// LayerNorm over 256, one wave per row. Optional relu, optional dup output.
// ---------------------------------------------------------------------------
__global__ __launch_bounds__(256) void ln256_kernel(const float* __restrict__ X,
                                                    float* __restrict__ Y,
                                                    float* __restrict__ Y2,
                                                    const float* __restrict__ gam,
                                                    const float* __restrict__ bet,
                                                    int relu) {
#pragma clang fp contract(off)
    int row = blockIdx.x * 4 + (threadIdx.x >> 6);
    int l = threadIdx.x & 63;
    float4 x = *(const float4*)(X + (size_t)row * 256 + l * 4);
    float s = x.x + x.y + x.z + x.w;
#pragma unroll
    for (int d = 1; d < 64; d <<= 1) s += __shfl_xor(s, d);
    float mu = s * (1.f / 256.f);
    float d0 = x.x - mu, d1 = x.y - mu, d2 = x.z - mu, d3 = x.w - mu;
    float ss = d0 * d0 + d1 * d1 + d2 * d2 + d3 * d3;
#pragma unroll
    for (int d = 1; d < 64; d <<= 1) ss += __shfl_xor(ss, d);
    float var = ss * (1.f / 256.f);
    float sd = sqrtf(var + 1e-5f);
    float4 y;
    y.x = (d0 / sd) * gam[l * 4 + 0] + bet[l * 4 + 0];
    y.y = (d1 / sd) * gam[l * 4 + 1] + bet[l * 4 + 1];
    y.z = (d2 / sd) * gam[l * 4 + 2] + bet[l * 4 + 2];
    y.w = (d3 / sd) * gam[l * 4 + 3] + bet[l * 4 + 3];
    if (relu) {
        y.x = fmaxf(y.x, 0.f); y.y = fmaxf(y.y, 0.f);
        y.z = fmaxf(y.z, 0.f); y.w = fmaxf(y.w, 0.f);
    }
    *(float4*)(Y + (size_t)row * 256 + l * 4) = y;
    if (Y2) *(float4*)(Y2 + (size_t)row * 256 + l * 4) = y;
}

// LayerNorm over 64 + tanh, one wave per row
__global__ __launch_bounds__(256) void ln64_tanh_kernel(const float* __restrict__ X,
                                                        float* __restrict__ Y,
                                                        const float* __restrict__ gam,
                                                        const float* __restrict__ bet) {
#pragma clang fp contract(off)
    int row = blockIdx.x * 4 + (threadIdx.x >> 6);
    int l = threadIdx.x & 63;
    float x = X[(size_t)row * 64 + l];
    float s = x;
#pragma unroll
    for (int d = 1; d < 64; d <<= 1) s += __shfl_xor(s, d);
    float mu = s * (1.f / 64.f);
    float dx = x - mu;
    float ss = dx * dx;
#pragma unroll
    for (int d = 1; d < 64; d <<= 1) ss += __shfl_xor(ss, d);
    float var = ss * (1.f / 64.f);
    float sd = sqrtf(var + 1e-5f);
    float y = tanhf((dx / sd) * gam[l] + bet[l]);
    Y[(size_t)row * 64 + l] = y;
}

// ---------------------------------------------------------------------------
// attention head: p = sigmoid(a2 @ Wa3 + ba3), flags = p > 0.4
// ---------------------------------------------------------------------------
__global__ __launch_bounds__(256) void attn_head_kernel(const float* __restrict__ a2,
                                                        const float* __restrict__ Wa3,
                                                        const float* __restrict__ ba3,
                                                        float* __restrict__ outP,
                                                        float* __restrict__ outInit,
                                                        int* __restrict__ flags) {
#pragma clang fp contract(off)
    int row = blockIdx.x * 4 + (threadIdx.x >> 6);
    int l = threadIdx.x & 63;
    float s = a2[(size_t)row * 128 + l] * Wa3[l] + a2[(size_t)row * 128 + 64 + l] * Wa3[64 + l];
#pragma unroll
    for (int d = 1; d < 64; d <<= 1) s += __shfl_xor(s, d);
    s += ba3[0];
    float p = 1.f / (1.f + expf(-s));
    if (l == 0) {
        outP[row] = p;
        int f = (p > 0.4f) ? 1 : 0;
        outInit[row] = f ? 1.f : 0.f;
        flags[row] = f;
    }
}

// ---------------------------------------------------------------------------
// batched dot: dot[b] = th_b @ th_b^T   (128x128, K=256); 2 blocks per batch
// ---------------------------------------------------------------------------
__global__ __launch_bounds__(256) void dot_kernel(const float* __restrict__ th,
                                                  float* __restrict__ dotm) {
    __shared__ float As[16][68];
    __shared__ float Bs[16][132];
    const int b = blockIdx.x >> 1, half = blockIdx.x & 1;
    const int t = threadIdx.x;
    const int tm = t >> 4, tn = t & 15;
    float acc[4][8] = {};
    const float* base = th + (size_t)b * 128 * 256;
    for (int k0 = 0; k0 < 256; k0 += 16) {
        {
            int r = t >> 2, kq = (t & 3) * 4;
            float4 v = *(const float4*)(base + (size_t)(half * 64 + r) * 256 + k0 + kq);
            As[kq + 0][r] = v.x; As[kq + 1][r] = v.y;
            As[kq + 2][r] = v.z; As[kq + 3][r] = v.w;
        }
        {
            int n = t >> 1, kq = (t & 1) * 8;
            const float* src = base + (size_t)n * 256 + k0 + kq;
            float4 v0 = *(const float4*)src;
            float4 v1 = *(const float4*)(src + 4);
            Bs[kq + 0][n] = v0.x; Bs[kq + 1][n] = v0.y;
            Bs[kq + 2][n] = v0.z; Bs[kq + 3][n] = v0.w;
            Bs[kq + 4][n] = v1.x; Bs[kq + 5][n] = v1.y;
            Bs[kq + 6][n] = v1.z; Bs[kq + 7][n] = v1.w;
        }
        __syncthreads();
#pragma unroll
        for (int kk = 0; kk < 16; ++kk) {
            float a[4], bb[8];
#pragma unroll
            for (int i = 0; i < 4; ++i) a[i] = As[kk][tm * 4 + i];
#pragma unroll
            for (int j = 0; j < 8; ++j) bb[j] = Bs[kk][tn * 8 + j];
#pragma unroll
            for (int i = 0; i < 4; ++i)
#pragma unroll
                for (int j = 0; j < 8; ++j) acc[i][j] = fmaf(a[i], bb[j], acc[i][j]);
        }
        __syncthreads();
    }
#pragma unroll
    for (int i = 0; i < 4; ++i)
#pragma unroll
        for (int j = 0; j < 8; ++j)
            dotm[(size_t)b * 16384 + (size_t)(half * 64 + tm * 4 + i) * 128 + tn * 8 + j] = acc[i][j];
}

__global__ void sq_kernel(const float* __restrict__ dotm, float* __restrict__ sq) {
    int i = blockIdx.x * 256 + threadIdx.x;   // 64 blocks
    int b = i >> 7, n = i & 127;
    sq[i] = dotm[(size_t)b * 16384 + (size_t)n * 129];
}

// ---------------------------------------------------------------------------
// top-16 smallest distances per row (ties -> lower index), write C + idx
// ---------------------------------------------------------------------------
__global__ __launch_bounds__(256) void topk_kernel(const float* __restrict__ dotm,
                                                   const float* __restrict__ sq,
                                                   const int* __restrict__ flags,
                                                   float* __restrict__ outC,
                                                   int* __restrict__ idxb) {
#pragma clang fp contract(off)
    int row = blockIdx.x * 4 + (threadIdx.x >> 6);
    int l = threadIdx.x & 63;
    int b = row >> 7;
    const float* drow = dotm + (size_t)row * 128;
    float sqi = sq[row];
    float t0 = 2.f * drow[l];
    float v0 = sq[b * 128 + l] - t0; v0 = v0 + sqi;
    float t1 = 2.f * drow[64 + l];
    float v1 = sq[b * 128 + 64 + l] - t1; v1 = v1 + sqi;

    unsigned long long mlo = 0ull, mhi = 0ull;
#pragma unroll 1
    for (int n = 0; n < 16; ++n) {
        float bv = v0; int bi = l;
        if (v1 < bv) { bv = v1; bi = 64 + l; }
#pragma unroll
        for (int d = 1; d < 64; d <<= 1) {
            float ov = __shfl_xor(bv, d);
            int oi = __shfl_xor(bi, d);
            if (ov < bv || (ov == bv && oi < bi)) { bv = ov; bi = oi; }
        }
        if (bi < 64) mlo |= (1ull << bi); else mhi |= (1ull << (bi - 64));
        if (l == bi) v0 = __builtin_inff();
        if (64 + l == bi) v1 = __builtin_inff();
    }
    float fl = (flags[row] != 0) ? 1.f : 0.f;
    outC[(size_t)row * 128 + l]      = fl * (((mlo >> l) & 1ull) ? 1.f : 0.f);
    outC[(size_t)row * 128 + 64 + l] = fl * (((mhi >> l) & 1ull) ? 1.f : 0.f);
    if (l < 16) {
        int cnt = 0, found = -1;
        for (int jj = 0; jj < 128; ++jj) {
            bool bit = (jj < 64) ? ((mlo >> jj) & 1ull) : ((mhi >> (jj - 64)) & 1ull);
            if (bit) { if (cnt == l) { found = jj; break; } ++cnt; }
        }
        idxb[(size_t)row * 16 + l] = found;
    }
}

// ---------------------------------------------------------------------------
// THE CHAIN: one 512-thread block per batch, both LSTM dirs fused.
// waves 0-3: fwd, waves 4-7: bwd. Wave wd owns hidden units [32wd,32wd+32),
// i/f/g/o in-lane. NO GLOBAL MEMORY OPS inside the 16-step recurrence:
// h snapshots land in LDS (hsnap) and are bulk-scattered once per agent.
// Fast v_exp/v_rcp activations; next-step xg prefetched before the barrier.
// ---------------------------------------------------------------------------
__global__ __launch_bounds__(512, 2) void chain_kernel(float* __restrict__ th,
                                                       const unsigned short* __restrict__ whhbf,
                                                       const unsigned short* __restrict__ wihbf,
                                                       const float* __restrict__ biasz,
                                                       const int* __restrict__ idxb,
                                                       const int* __restrict__ flags) {
    const int b = blockIdx.x;
    const int t = threadIdx.x;
    const int l = t & 63, lr = l & 15, lg = l >> 4;
    const int w = t >> 6, dir = w >> 2, wd = w & 3;

    __shared__ __align__(16) short grpb[4096];                 // 16x256 bf16, xor-swizzled
    __shared__ __align__(16) unsigned short xgs[2 * 16 * 520]; // gate pre-acts, bf16
    __shared__ __align__(16) float hsnap[2][16][128];          // per-member h (fp32, exact)
    __shared__ __align__(16) unsigned short hbufs[2][2][128];  // ping-pong h (bf16)
    __shared__ int gis[16];
    __shared__ int flg[128];

    // resident Whh bf16 B-fragments
    bf16x8 wf[4][2][4];
    {
        const unsigned short* whh = whhbf + (size_t)dir * 65536;
#pragma unroll
        for (int G = 0; G < 4; ++G)
#pragma unroll
            for (int hf = 0; hf < 2; ++hf) {
                int gate = G * 128 + wd * 32 + hf * 16 + lr;
#pragma unroll
                for (int kc = 0; kc < 4; ++kc)
                    wf[G][hf][kc] = *(const bf16x8*)(whh + (size_t)gate * 128 + kc * 32 + lg * 8);
            }
    }
    const unsigned short* wih = wihbf + (size_t)dir * 131072;
    float bzr[8];
#pragma unroll
    for (int ct = 0; ct < 8; ++ct) bzr[ct] = biasz[dir * 512 + wd * 128 + ct * 16 + lr];

    if (t < 128) flg[t] = flags[b * 128 + t];
    __syncthreads();

    for (int ag = 0; ag < 128; ++ag) {
        if (!flg[ag]) continue;
        __syncthreads();   // prior scatter drained; gis free to overwrite
        if (t < 16) gis[t] = idxb[(size_t)(b * 128 + ag) * 16 + t];
        __syncthreads();

        // gather 16 group rows -> bf16 LDS (swizzled); zero h ping-buffer 0
        {
            int m = t >> 5, c = t & 31;
            const float* src = th + (size_t)(b * 128 + gis[m]) * 256 + c * 8;
            float4 v0 = *(const float4*)src;
            float4 v1 = *(const float4*)(src + 4);
            bf16x8 sv;
            sv[0] = (short)f2bf(v0.x); sv[1] = (short)f2bf(v0.y);
            sv[2] = (short)f2bf(v0.z); sv[3] = (short)f2bf(v0.w);
            sv[4] = (short)f2bf(v1.x); sv[5] = (short)f2bf(v1.y);
            sv[6] = (short)f2bf(v1.z); sv[7] = (short)f2bf(v1.w);
            int byteoff = m * 512 + ((c * 16) ^ ((m & 7) << 4));
            *reinterpret_cast<bf16x8*>(reinterpret_cast<char*>(grpb) + byteoff) = sv;
            if (t < 256) ((unsigned short*)hbufs)[t] = 0;
        }
        __syncthreads();

        // xg = grp @ Wih^T + (bih+bhh): wave owns 128 gates [wd*128, wd*128+128)
        {
            f32x4 xa[8];
#pragma unroll
            for (int ct = 0; ct < 8; ++ct) xa[ct] = (f32x4){0.f, 0.f, 0.f, 0.f};
#pragma unroll
            for (int kc = 0; kc < 8; ++kc) {
                int abyte = lr * 512 + ((kc * 64 + lg * 16) ^ ((lr & 7) << 4));
                bf16x8 af = *reinterpret_cast<const bf16x8*>(
                    reinterpret_cast<const char*>(grpb) + abyte);
#pragma unroll
                for (int ct = 0; ct < 8; ++ct) {
                    const unsigned short* wb =
                        wih + (size_t)(wd * 128 + ct * 16 + lr) * 256 + kc * 32 + lg * 8;
                    xa[ct] = __builtin_amdgcn_mfma_f32_16x16x32_bf16(
                        af, *(const bf16x8*)wb, xa[ct], 0, 0, 0);
                }
            }
#pragma unroll
            for (int ct = 0; ct < 8; ++ct) {
                int g = wd * 128 + ct * 16 + lr;
#pragma unroll
                for (int r = 0; r < 4; ++r) {
                    int m = lg * 4 + r;
                    xgs[(dir * 16 + m) * 520 + g] = f2bf(xa[ct][r] + bzr[ct]);
                }
            }
        }
        __syncthreads();   // xgs ready

        // preload xg for first step
        float xgv[8];
        {
            int m0 = dir ? 15 : 0;
            const unsigned short* xgm = &xgs[(dir * 16 + m0) * 520];
#pragma unroll
            for (int hf = 0; hf < 2; ++hf)
#pragma unroll
                for (int G = 0; G < 4; ++G)
                    xgv[hf * 4 + G] = bf2f(xgm[G * 128 + wd * 32 + hf * 16 + lr]);
        }

        // 16-step recurrence: LDS + MFMA + VALU only, 1 barrier per step
        float cst0 = 0.f, cst1 = 0.f;
        for (int s = 0; s < 16; ++s) {
            const int m = dir ? (15 - s) : s;
            const int p = s & 1;
            f32x4 acc[8];
#pragma unroll
            for (int ct = 0; ct < 8; ++ct) acc[ct] = (f32x4){0.f, 0.f, 0.f, 0.f};
#pragma unroll
            for (int kc = 0; kc < 4; ++kc) {
                bf16x8 ha = *reinterpret_cast<const bf16x8*>(&hbufs[p][dir][kc * 32 + lg * 8]);
#pragma unroll
                for (int G = 0; G < 4; ++G) {
                    acc[G * 2 + 0] = __builtin_amdgcn_mfma_f32_16x16x32_bf16(
                        ha, wf[G][0][kc], acc[G * 2 + 0], 0, 0, 0);
                    acc[G * 2 + 1] = __builtin_amdgcn_mfma_f32_16x16x32_bf16(
                        ha, wf[G][1][kc], acc[G * 2 + 1], 0, 0, 0);
                }
            }
            float zi0 = acc[0][0] + xgv[0], zf0 = acc[2][0] + xgv[1];
            float zg0 = acc[4][0] + xgv[2], zo0 = acc[6][0] + xgv[3];
            float zi1 = acc[1][0] + xgv[4], zf1 = acc[3][0] + xgv[5];
            float zg1 = acc[5][0] + xgv[6], zo1 = acc[7][0] + xgv[7];
            float i0 = fsig(zi0), f0 = fsig(zf0), g0 = ftanh(zg0), o0 = fsig(zo0);
            cst0 = f0 * cst0 + i0 * g0;
            float h0 = o0 * ftanh(cst0);
            float i1 = fsig(zi1), f1 = fsig(zf1), g1 = ftanh(zg1), o1 = fsig(zo1);
            cst1 = f1 * cst1 + i1 * g1;
            float h1 = o1 * ftanh(cst1);
            if (l < 16) {
                int j0 = wd * 32 + lr;
                hbufs[p ^ 1][dir][j0]      = f2bf(h0);
                hbufs[p ^ 1][dir][j0 + 16] = f2bf(h1);
                hsnap[dir][m][j0]      = h0;
                hsnap[dir][m][j0 + 16] = h1;
            }
            // prefetch next step's xg (hides ds latency under barrier wait)
            if (s < 15) {
                int mn = dir ? (14 - s) : (s + 1);
                const unsigned short* xgm = &xgs[(dir * 16 + mn) * 520];
#pragma unroll
                for (int hf = 0; hf < 2; ++hf)
#pragma unroll
                    for (int G = 0; G < 4; ++G)
                        xgv[hf * 4 + G] = bf2f(xgm[G * 128 + wd * 32 + hf * 16 + lr]);
            }
            __syncthreads();
        }

        // bulk scatter: all 16 member rows, coalesced float4
        {
            int m = t >> 5, d2 = (t >> 4) & 1, c8 = (t & 15) * 8;
            const float* sp = &hsnap[d2][m][c8];
            float4 v0 = *(const float4*)sp;
            float4 v1 = *(const float4*)(sp + 4);
            float* dst = th + (size_t)(b * 128 + gis[m]) * 256 + d2 * 128 + c8;
            *(float4*)dst = v0;
            *(float4*)(dst + 4) = v1;
        }
    }
}

// ---------------------------------------------------------------------------
extern "C" void kernel_launch(void* const* d_in, const int* in_sizes, int n_in,
                              void* d_out, int out_size, void* d_ws, size_t ws_size,
                              hipStream_t stream) {
    const float* obs  = (const float*)d_in[0];
    const float* W1   = (const float*)d_in[1];
    const float* b1   = (const float*)d_in[2];
    const float* gg1  = (const float*)d_in[3];
    const float* be1  = (const float*)d_in[4];
    const float* W2   = (const float*)d_in[5];
    const float* b2   = (const float*)d_in[6];
    const float* gg2  = (const float*)d_in[7];
    const float* be2  = (const float*)d_in[8];
    const float* Wa1  = (const float*)d_in[9];
    const float* ba1  = (const float*)d_in[10];
    const float* Wa2  = (const float*)d_in[11];
    const float* ba2  = (const float*)d_in[12];
    const float* Wa3  = (const float*)d_in[13];
    const float* ba3  = (const float*)d_in[14];
    const float* Wf_ih = (const float*)d_in[15];
    const float* Wf_hh = (const float*)d_in[16];
    const float* bf_ih = (const float*)d_in[17];
    const float* bf_hh = (const float*)d_in[18];
    const float* Wb_ih = (const float*)d_in[19];
    const float* Wb_hh = (const float*)d_in[20];
    const float* bb_ih = (const float*)d_in[21];
    const float* bb_hh = (const float*)d_in[22];
    const float* W3   = (const float*)d_in[23];
    const float* b3   = (const float*)d_in[24];
    const float* gg3  = (const float*)d_in[25];
    const float* be3  = (const float*)d_in[26];
    const float* W4   = (const float*)d_in[27];
    const float* b4   = (const float*)d_in[28];
    const float* gg4  = (const float*)d_in[29];
    const float* be4  = (const float*)d_in[30];

    float* out     = (float*)d_out;
    float* out_acts = out;                   // 128*128*64
    float* out_C    = out + 1048576;         // 128*128*128
    float* out_ip   = out + 3145728;         // 16384
    float* out_ii   = out + 3162112;         // 16384
    float* out_nt   = out + 3178496;         // 128*128*256 (evolving thoughts)
    float* out_ot   = out + 7372800;         // 128*128*256 (old thoughts)

    float* ws    = (float*)d_ws;
    float* h1    = ws;                               // 4194304
    float* abuf  = ws + 4194304;                     // 2097152 (a1, later dot)
    float* a2buf = ws + 6291456;                     // 2097152 (a2, later act-pre)
    unsigned short* wihbf = (unsigned short*)(ws + 8388608);  // 262144 shorts
    float* biasz = ws + 8519680;                     // 1024
    unsigned short* whhbf = (unsigned short*)(ws + 8520704);  // 131072 shorts
    float* sqb   = ws + 8586240;                     // 16384
    int* idxb    = (int*)(ws + 8602624);             // 262144
    int* flagsb  = (int*)(ws + 8864768);             // 16384

    prep_kernel<<<512, 256, 0, stream>>>(Wf_ih, Wb_ih, Wf_hh, Wb_hh,
                                         bf_ih, bf_hh, bb_ih, bb_hh,
                                         wihbf, whhbf, biasz);

    // actor_1
    gemm64<<<dim3(4, 256), 256, 0, stream>>>(obs, W1, b1, h1, 16384, 256, 512, 0);
    ln256_kernel<<<4096, 256, 0, stream>>>(h1, h1, nullptr, gg1, be1, 1);
    gemm64<<<dim3(4, 256), 256, 0, stream>>>(h1, W2, b2, out_nt, 16384, 256, 256, 0);
    ln256_kernel<<<4096, 256, 0, stream>>>(out_nt, out_nt, out_ot, gg2, be2, 0);

    // attention unit
    gemm64<<<dim3(2, 256), 256, 0, stream>>>(out_nt, Wa1, ba1, abuf, 16384, 128, 256, 1);
    gemm64<<<dim3(2, 256), 256, 0, stream>>>(abuf, Wa2, ba2, a2buf, 16384, 128, 128, 1);
    attn_head_kernel<<<4096, 256, 0, stream>>>(a2buf, Wa3, ba3, out_ip, out_ii, flagsb);

    // pairwise distances + top-16
    dot_kernel<<<256, 256, 0, stream>>>(out_nt, abuf);
    sq_kernel<<<64, 256, 0, stream>>>(abuf, sqb);
    topk_kernel<<<4096, 256, 0, stream>>>(abuf, sqb, flagsb, out_C, idxb);

    // sequential communication chain (mutates out_nt), both dirs fused per block
    chain_kernel<<<128, 512, 0, stream>>>(out_nt, whhbf, wihbf, biasz, idxb, flagsb);

    // actor_2
    gemm64<<<dim3(4, 256), 256, 0, stream>>>(out_nt, W3, b3, h1, 16384, 256, 256, 2);
    ln256_kernel<<<4096, 256, 0, stream>>>(h1, h1, nullptr, gg3, be3, 0);
    gemm64<<<dim3(1, 256), 256, 0, stream>>>(h1, W4, b4, a2buf, 16384, 64, 256, 0);
    ln64_tanh_kernel<<<4096, 256, 0, stream>>>(a2buf, out_acts, gg4, be4);
}

// Round 4
// 3967.012 us; speedup vs baseline: 1.2578x; 1.1835x over previous
//
#include <hip/hip_runtime.h>
#include <math.h>

typedef __attribute__((ext_vector_type(8))) short bf16x8;
typedef __attribute__((ext_vector_type(4))) float f32x4;

__device__ __forceinline__ unsigned short f2bf(float x) {
    unsigned int u = __float_as_uint(x);
    u += 0x7fffu + ((u >> 16) & 1u);
    return (unsigned short)(u >> 16);
}
__device__ __forceinline__ float bf2f(unsigned short b) {
    return __uint_as_float(((unsigned int)b) << 16);
}
// fast activations: v_exp_f32 + v_rcp_f32 (rel err ~1e-7, far below bf16 noise)
__device__ __forceinline__ float fsig(float z) {
    float e = __expf(-z);
    return __builtin_amdgcn_rcpf(1.f + e);
}
__device__ __forceinline__ float ftanh(float x) {
    float ax = fabsf(x);
    float e = __expf(-2.f * ax);
    float r = (1.f - e) * __builtin_amdgcn_rcpf(1.f + e);
    return copysignf(r, x);
}
__device__ __forceinline__ bf16x8 pack8(float4 a, float4 b) {
    bf16x8 r;
    r[0] = (short)f2bf(a.x); r[1] = (short)f2bf(a.y);
    r[2] = (short)f2bf(a.z); r[3] = (short)f2bf(a.w);
    r[4] = (short)f2bf(b.x); r[5] = (short)f2bf(b.y);
    r[6] = (short)f2bf(b.z); r[7] = (short)f2bf(b.w);
    return r;
}

// ---------------------------------------------------------------------------
// prep: convert Wih and Whh to bf16, bias sums
// ---------------------------------------------------------------------------
__global__ void prep_kernel(const float* __restrict__ Wf_ih, const float* __restrict__ Wb_ih,
                            const float* __restrict__ Wf_hh, const float* __restrict__ Wb_hh,
                            const float* __restrict__ bf_ih, const float* __restrict__ bf_hh,
                            const float* __restrict__ bb_ih, const float* __restrict__ bb_hh,
                            unsigned short* __restrict__ wihbf,
                            unsigned short* __restrict__ whhbf,
                            float* __restrict__ biasz) {
    int i = blockIdx.x * 256 + threadIdx.x;   // grid 512*256 = 131072
    if (i < 131072) {
        wihbf[i]          = f2bf(Wf_ih[i]);
        wihbf[131072 + i] = f2bf(Wb_ih[i]);
    }
    if (i < 65536) {
        whhbf[i]         = f2bf(Wf_hh[i]);
        whhbf[65536 + i] = f2bf(Wb_hh[i]);
    }
    if (i < 512) {
        biasz[i]       = bf_ih[i] + bf_hh[i];
        biasz[512 + i] = bb_ih[i] + bb_hh[i];
    }
}

// ---------------------------------------------------------------------------
// generic fp32 GEMM  C[M,N] = A[M,K] @ B[K,N] + bias ; flags: 1=relu_out 2=relu_A
// ---------------------------------------------------------------------------
__global__ __launch_bounds__(256) void gemm64(const float* __restrict__ A,
                                              const float* __restrict__ Bm,
                                              const float* __restrict__ bias,
                                              float* __restrict__ C,
                                              int M, int N, int K, int flags) {
    __shared__ float As[16][68];
    __shared__ float Bs[16][68];
    const int t = threadIdx.x;
    const int row0 = blockIdx.y * 64, col0 = blockIdx.x * 64;
    const int tm = t >> 4, tn = t & 15;
    float acc[4][4] = {};
    for (int k0 = 0; k0 < K; k0 += 16) {
        {
            int r = t >> 2, kq = (t & 3) * 4;
            float4 v = *(const float4*)(A + (size_t)(row0 + r) * K + k0 + kq);
            if (flags & 2) {
                v.x = fmaxf(v.x, 0.f); v.y = fmaxf(v.y, 0.f);
                v.z = fmaxf(v.z, 0.f); v.w = fmaxf(v.w, 0.f);
            }
            As[kq + 0][r] = v.x; As[kq + 1][r] = v.y;
            As[kq + 2][r] = v.z; As[kq + 3][r] = v.w;
        }
        {
            int kk = t >> 4, nq = (t & 15) * 4;
            float4 v = *(const float4*)(Bm + (size_t)(k0 + kk) * N + col0 + nq);
            *(float4*)&Bs[kk][nq] = v;
        }
        __syncthreads();
#pragma unroll
        for (int kk = 0; kk < 16; ++kk) {
            float a[4], b[4];
#pragma unroll
            for (int i = 0; i < 4; ++i) a[i] = As[kk][tm * 4 + i];
#pragma unroll
            for (int j = 0; j < 4; ++j) b[j] = Bs[kk][tn * 4 + j];
#pragma unroll
            for (int i = 0; i < 4; ++i)
#pragma unroll
                for (int j = 0; j < 4; ++j) acc[i][j] = fmaf(a[i], b[j], acc[i][j]);
        }
        __syncthreads();
    }
#pragma unroll
    for (int i = 0; i < 4; ++i) {
#pragma unroll
        for (int j = 0; j < 4; ++j) {
            int col = col0 + tn * 4 + j;
            float v = acc[i][j] + (bias ? bias[col] : 0.f);
            if (flags & 1) v = fmaxf(v, 0.f);
            C[(size_t)(row0 + tm * 4 + i) * N + col] = v;
        }
    }
}

// ---------------------------------------------------------------------------
// LayerNorm over 256, one wave per row. Optional relu, optional dup output.
// ---------------------------------------------------------------------------
__global__ __launch_bounds__(256) void ln256_kernel(const float* __restrict__ X,
                                                    float* __restrict__ Y,
                                                    float* __restrict__ Y2,
                                                    const float* __restrict__ gam,
                                                    const float* __restrict__ bet,
                                                    int relu) {
#pragma clang fp contract(off)
    int row = blockIdx.x * 4 + (threadIdx.x >> 6);
    int l = threadIdx.x & 63;
    float4 x = *(const float4*)(X + (size_t)row * 256 + l * 4);
    float s = x.x + x.y + x.z + x.w;
#pragma unroll
    for (int d = 1; d < 64; d <<= 1) s += __shfl_xor(s, d);
    float mu = s * (1.f / 256.f);
    float d0 = x.x - mu, d1 = x.y - mu, d2 = x.z - mu, d3 = x.w - mu;
    float ss = d0 * d0 + d1 * d1 + d2 * d2 + d3 * d3;
#pragma unroll
    for (int d = 1; d < 64; d <<= 1) ss += __shfl_xor(ss, d);
    float var = ss * (1.f / 256.f);
    float sd = sqrtf(var + 1e-5f);
    float4 y;
    y.x = (d0 / sd) * gam[l * 4 + 0] + bet[l * 4 + 0];
    y.y = (d1 / sd) * gam[l * 4 + 1] + bet[l * 4 + 1];
    y.z = (d2 / sd) * gam[l * 4 + 2] + bet[l * 4 + 2];
    y.w = (d3 / sd) * gam[l * 4 + 3] + bet[l * 4 + 3];
    if (relu) {
        y.x = fmaxf(y.x, 0.f); y.y = fmaxf(y.y, 0.f);
        y.z = fmaxf(y.z, 0.f); y.w = fmaxf(y.w, 0.f);
    }
    *(float4*)(Y + (size_t)row * 256 + l * 4) = y;
    if (Y2) *(float4*)(Y2 + (size_t)row * 256 + l * 4) = y;
}

// LayerNorm over 64 + tanh, one wave per row
__global__ __launch_bounds__(256) void ln64_tanh_kernel(const float* __restrict__ X,
                                                        float* __restrict__ Y,
                                                        const float* __restrict__ gam,
                                                        const float* __restrict__ bet) {
#pragma clang fp contract(off)
    int row = blockIdx.x * 4 + (threadIdx.x >> 6);
    int l = threadIdx.x & 63;
    float x = X[(size_t)row * 64 + l];
    float s = x;
#pragma unroll
    for (int d = 1; d < 64; d <<= 1) s += __shfl_xor(s, d);
    float mu = s * (1.f / 64.f);
    float dx = x - mu;
    float ss = dx * dx;
#pragma unroll
    for (int d = 1; d < 64; d <<= 1) ss += __shfl_xor(ss, d);
    float var = ss * (1.f / 64.f);
    float sd = sqrtf(var + 1e-5f);
    float y = tanhf((dx / sd) * gam[l] + bet[l]);
    Y[(size_t)row * 64 + l] = y;
}

// ---------------------------------------------------------------------------
// attention head: p = sigmoid(a2 @ Wa3 + ba3), flags = p > 0.4
// ---------------------------------------------------------------------------
__global__ __launch_bounds__(256) void attn_head_kernel(const float* __restrict__ a2,
                                                        const float* __restrict__ Wa3,
                                                        const float* __restrict__ ba3,
                                                        float* __restrict__ outP,
                                                        float* __restrict__ outInit,
                                                        int* __restrict__ flags) {
#pragma clang fp contract(off)
    int row = blockIdx.x * 4 + (threadIdx.x >> 6);
    int l = threadIdx.x & 63;
    float s = a2[(size_t)row * 128 + l] * Wa3[l] + a2[(size_t)row * 128 + 64 + l] * Wa3[64 + l];
#pragma unroll
    for (int d = 1; d < 64; d <<= 1) s += __shfl_xor(s, d);
    s += ba3[0];
    float p = 1.f / (1.f + expf(-s));
    if (l == 0) {
        outP[row] = p;
        int f = (p > 0.4f) ? 1 : 0;
        outInit[row] = f ? 1.f : 0.f;
        flags[row] = f;
    }
}

// ---------------------------------------------------------------------------
// batched dot: dot[b] = th_b @ th_b^T   (128x128, K=256); 2 blocks per batch
// ---------------------------------------------------------------------------
__global__ __launch_bounds__(256) void dot_kernel(const float* __restrict__ th,
                                                  float* __restrict__ dotm) {
    __shared__ float As[16][68];
    __shared__ float Bs[16][132];
    const int b = blockIdx.x >> 1, half = blockIdx.x & 1;
    const int t = threadIdx.x;
    const int tm = t >> 4, tn = t & 15;
    float acc[4][8] = {};
    const float* base = th + (size_t)b * 128 * 256;
    for (int k0 = 0; k0 < 256; k0 += 16) {
        {
            int r = t >> 2, kq = (t & 3) * 4;
            float4 v = *(const float4*)(base + (size_t)(half * 64 + r) * 256 + k0 + kq);
            As[kq + 0][r] = v.x; As[kq + 1][r] = v.y;
            As[kq + 2][r] = v.z; As[kq + 3][r] = v.w;
        }
        {
            int n = t >> 1, kq = (t & 1) * 8;
            const float* src = base + (size_t)n * 256 + k0 + kq;
            float4 v0 = *(const float4*)src;
            float4 v1 = *(const float4*)(src + 4);
            Bs[kq + 0][n] = v0.x; Bs[kq + 1][n] = v0.y;
            Bs[kq + 2][n] = v0.z; Bs[kq + 3][n] = v0.w;
            Bs[kq + 4][n] = v1.x; Bs[kq + 5][n] = v1.y;
            Bs[kq + 6][n] = v1.z; Bs[kq + 7][n] = v1.w;
        }
        __syncthreads();
#pragma unroll
        for (int kk = 0; kk < 16; ++kk) {
            float a[4], bb[8];
#pragma unroll
            for (int i = 0; i < 4; ++i) a[i] = As[kk][tm * 4 + i];
#pragma unroll
            for (int j = 0; j < 8; ++j) bb[j] = Bs[kk][tn * 8 + j];
#pragma unroll
            for (int i = 0; i < 4; ++i)
#pragma unroll
                for (int j = 0; j < 8; ++j) acc[i][j] = fmaf(a[i], bb[j], acc[i][j]);
        }
        __syncthreads();
    }
#pragma unroll
    for (int i = 0; i < 4; ++i)
#pragma unroll
        for (int j = 0; j < 8; ++j)
            dotm[(size_t)b * 16384 + (size_t)(half * 64 + tm * 4 + i) * 128 + tn * 8 + j] = acc[i][j];
}

__global__ void sq_kernel(const float* __restrict__ dotm, float* __restrict__ sq) {
    int i = blockIdx.x * 256 + threadIdx.x;   // 64 blocks
    int b = i >> 7, n = i & 127;
    sq[i] = dotm[(size_t)b * 16384 + (size_t)n * 129];
}

// ---------------------------------------------------------------------------
// top-16 smallest distances per row (ties -> lower index), write C + idx
// ---------------------------------------------------------------------------
__global__ __launch_bounds__(256) void topk_kernel(const float* __restrict__ dotm,
                                                   const float* __restrict__ sq,
                                                   const int* __restrict__ flags,
                                                   float* __restrict__ outC,
                                                   int* __restrict__ idxb) {
#pragma clang fp contract(off)
    int row = blockIdx.x * 4 + (threadIdx.x >> 6);
    int l = threadIdx.x & 63;
    int b = row >> 7;
    const float* drow = dotm + (size_t)row * 128;
    float sqi = sq[row];
    float t0 = 2.f * drow[l];
    float v0 = sq[b * 128 + l] - t0; v0 = v0 + sqi;
    float t1 = 2.f * drow[64 + l];
    float v1 = sq[b * 128 + 64 + l] - t1; v1 = v1 + sqi;

    unsigned long long mlo = 0ull, mhi = 0ull;
#pragma unroll 1
    for (int n = 0; n < 16; ++n) {
        float bv = v0; int bi = l;
        if (v1 < bv) { bv = v1; bi = 64 + l; }
#pragma unroll
        for (int d = 1; d < 64; d <<= 1) {
            float ov = __shfl_xor(bv, d);
            int oi = __shfl_xor(bi, d);
            if (ov < bv || (ov == bv && oi < bi)) { bv = ov; bi = oi; }
        }
        if (bi < 64) mlo |= (1ull << bi); else mhi |= (1ull << (bi - 64));
        if (l == bi) v0 = __builtin_inff();
        if (64 + l == bi) v1 = __builtin_inff();
    }
    float fl = (flags[row] != 0) ? 1.f : 0.f;
    outC[(size_t)row * 128 + l]      = fl * (((mlo >> l) & 1ull) ? 1.f : 0.f);
    outC[(size_t)row * 128 + 64 + l] = fl * (((mhi >> l) & 1ull) ? 1.f : 0.f);
    if (l < 16) {
        int cnt = 0, found = -1;
        for (int jj = 0; jj < 128; ++jj) {
            bool bit = (jj < 64) ? ((mlo >> jj) & 1ull) : ((mhi >> (jj - 64)) & 1ull);
            if (bit) { if (cnt == l) { found = jj; break; } ++cnt; }
        }
        idxb[(size_t)row * 16 + l] = found;
    }
}

// ---------------------------------------------------------------------------
// THE CHAIN: one 1024-thread block per batch (16 waves: 8 fwd, 8 bwd).
// The whole th batch-slice lives in LDS (bf16, row-XOR-swizzled) for the
// entire chain: gather/scatter/xg are pure LDS ops. Wave wd of a dir owns
// 16 hidden units -> Whh residency = 16 bf16x8 fragments = 64 VGPRs (no
// spill by construction). i/f/g/o of unit j land in-lane; 1 barrier/step.
// Global traffic inside the agent loop: Wih B-fragments only (L2-hot).
// ---------------------------------------------------------------------------
__global__ __launch_bounds__(1024, 4) void chain_kernel(float* __restrict__ th,
                                                        const unsigned short* __restrict__ whhbf,
                                                        const unsigned short* __restrict__ wihbf,
                                                        const float* __restrict__ biasz,
                                                        const int* __restrict__ idxb,
                                                        const int* __restrict__ flags) {
    const int b = blockIdx.x;
    const int t = threadIdx.x;
    const int l = t & 63, lr = l & 15, lg = l >> 4;
    const int w = t >> 6, dir = w >> 3, wd = w & 7;

    __shared__ __align__(16) unsigned short thl[128 * 256];     // 64 KB, row-swizzled bf16
    __shared__ __align__(16) unsigned short xgs[2 * 16 * 520];  // 33 KB gate pre-acts
    __shared__ __align__(16) unsigned short hbufs[2][2][128];   // 1 KB ping-pong h
    __shared__ int idxl[128 * 16];                              // 8 KB neighbor indices
    __shared__ int flg[128];

    // ---- load th slice -> bf16 LDS (swizzled). thread: row r=t>>3, 32 floats
    {
        int r = t >> 3, c0 = (t & 7) * 32;
        const float* src = th + (size_t)(b * 128 + r) * 256 + c0;
        char* rowb = (char*)thl + r * 512;
        int swz = (r & 7) << 4;
#pragma unroll
        for (int i = 0; i < 4; ++i) {
            float4 v0 = *(const float4*)(src + i * 8);
            float4 v1 = *(const float4*)(src + i * 8 + 4);
            *(bf16x8*)(rowb + (((c0 + i * 8) * 2) ^ swz)) = pack8(v0, v1);
        }
    }
    if (t < 128) flg[t] = flags[b * 128 + t];
    idxl[t] = idxb[(size_t)b * 2048 + t];
    idxl[t + 1024] = idxb[(size_t)b * 2048 + 1024 + t];

    // ---- resident Whh bf16 B-fragments: 16 frags = 64 VGPRs
    bf16x8 wf[4][4];
    {
        const unsigned short* whh = whhbf + (size_t)dir * 65536;
#pragma unroll
        for (int G = 0; G < 4; ++G) {
            int gate = G * 128 + wd * 16 + lr;
#pragma unroll
            for (int kc = 0; kc < 4; ++kc)
                wf[G][kc] = *(const bf16x8*)(whh + (size_t)gate * 128 + kc * 32 + lg * 8);
        }
    }
    const unsigned short* wih = wihbf + (size_t)dir * 131072;
    float bzr[4];
#pragma unroll
    for (int ct = 0; ct < 4; ++ct) bzr[ct] = biasz[dir * 512 + wd * 64 + ct * 16 + lr];
    __syncthreads();

    for (int ag = 0; ag < 128; ++ag) {
        if (!flg[ag]) continue;
        const int* gi = &idxl[ag * 16];
        const int myrow = gi[lr];
        const int myswz = (myrow & 7) << 4;
        const char* arow = (const char*)thl + myrow * 512;

        if (t < 512) ((unsigned short*)hbufs)[t] = 0;   // zero both h ping-buffers

        // xg = grp @ Wih^T + bias: wave owns 64 gates [wd*64, wd*64+64)
        {
            f32x4 xa[4];
#pragma unroll
            for (int ct = 0; ct < 4; ++ct) xa[ct] = (f32x4){0.f, 0.f, 0.f, 0.f};
#pragma unroll
            for (int kc = 0; kc < 8; ++kc) {
                bf16x8 af = *(const bf16x8*)(arow + ((kc * 64 + lg * 16) ^ myswz));
#pragma unroll
                for (int ct = 0; ct < 4; ++ct) {
                    const unsigned short* wb =
                        wih + (size_t)(wd * 64 + ct * 16 + lr) * 256 + kc * 32 + lg * 8;
                    xa[ct] = __builtin_amdgcn_mfma_f32_16x16x32_bf16(
                        af, *(const bf16x8*)wb, xa[ct], 0, 0, 0);
                }
            }
#pragma unroll
            for (int ct = 0; ct < 4; ++ct) {
                int g = wd * 64 + ct * 16 + lr;
#pragma unroll
                for (int r = 0; r < 4; ++r) {
                    int m = lg * 4 + r;
                    xgs[(dir * 16 + m) * 520 + g] = f2bf(xa[ct][r] + bzr[ct]);
                }
            }
        }
        __syncthreads();   // xgs + hbuf zero ready

        // preload xg for first step
        float xgv[4];
        {
            int m0 = dir ? 15 : 0;
            const unsigned short* xm = &xgs[(dir * 16 + m0) * 520 + wd * 16 + lr];
#pragma unroll
            for (int G = 0; G < 4; ++G) xgv[G] = bf2f(xm[G * 128]);
        }

        // 16-step recurrence: LDS + MFMA + VALU only, 1 barrier per step
        float cst = 0.f;
#pragma unroll 2
        for (int s = 0; s < 16; ++s) {
            const int m = dir ? (15 - s) : s;
            const int p = s & 1;
            f32x4 acc[4];
#pragma unroll
            for (int G = 0; G < 4; ++G) acc[G] = (f32x4){0.f, 0.f, 0.f, 0.f};
#pragma unroll
            for (int kc = 0; kc < 4; ++kc) {
                bf16x8 ha = *(const bf16x8*)(&hbufs[p][dir][kc * 32 + lg * 8]);
#pragma unroll
                for (int G = 0; G < 4; ++G)
                    acc[G] = __builtin_amdgcn_mfma_f32_16x16x32_bf16(ha, wf[G][kc], acc[G], 0, 0, 0);
            }
            float zi = acc[0][0] + xgv[0];
            float zf = acc[1][0] + xgv[1];
            float zg = acc[2][0] + xgv[2];
            float zo = acc[3][0] + xgv[3];
            float ig = fsig(zi), fg = fsig(zf), gv = ftanh(zg), og = fsig(zo);
            cst = fg * cst + ig * gv;
            float h = og * ftanh(cst);
            int rowm = gi[m];
            if (lg == 0) {
                int j = wd * 16 + lr;
                hbufs[p ^ 1][dir][j] = f2bf(h);
                int col = dir * 128 + j;
                *(unsigned short*)((char*)thl + rowm * 512 + ((col * 2) ^ ((rowm & 7) << 4))) =
                    f2bf(h);
            }
            if (s < 15) {
                int mn = dir ? (14 - s) : (s + 1);
                const unsigned short* xm = &xgs[(dir * 16 + mn) * 520 + wd * 16 + lr];
#pragma unroll
                for (int G = 0; G < 4; ++G) xgv[G] = bf2f(xm[G * 128]);
            }
            __syncthreads();
        }
    }

    // ---- write back the whole slice (un-swizzle, bf16 -> fp32)
    __syncthreads();
    {
        int r = t >> 3, c0 = (t & 7) * 32;
        const char* rowb = (const char*)thl + r * 512;
        int swz = (r & 7) << 4;
        float* dst = th + (size_t)(b * 128 + r) * 256 + c0;
#pragma unroll
        for (int i = 0; i < 4; ++i) {
            bf16x8 sv = *(const bf16x8*)(rowb + (((c0 + i * 8) * 2) ^ swz));
            float4 v0, v1;
            v0.x = bf2f((unsigned short)sv[0]); v0.y = bf2f((unsigned short)sv[1]);
            v0.z = bf2f((unsigned short)sv[2]); v0.w = bf2f((unsigned short)sv[3]);
            v1.x = bf2f((unsigned short)sv[4]); v1.y = bf2f((unsigned short)sv[5]);
            v1.z = bf2f((unsigned short)sv[6]); v1.w = bf2f((unsigned short)sv[7]);
            *(float4*)(dst + i * 8) = v0;
            *(float4*)(dst + i * 8 + 4) = v1;
        }
    }
}

// ---------------------------------------------------------------------------
extern "C" void kernel_launch(void* const* d_in, const int* in_sizes, int n_in,
                              void* d_out, int out_size, void* d_ws, size_t ws_size,
                              hipStream_t stream) {
    const float* obs  = (const float*)d_in[0];
    const float* W1   = (const float*)d_in[1];
    const float* b1   = (const float*)d_in[2];
    const float* gg1  = (const float*)d_in[3];
    const float* be1  = (const float*)d_in[4];
    const float* W2   = (const float*)d_in[5];
    const float* b2   = (const float*)d_in[6];
    const float* gg2  = (const float*)d_in[7];
    const float* be2  = (const float*)d_in[8];
    const float* Wa1  = (const float*)d_in[9];
    const float* ba1  = (const float*)d_in[10];
    const float* Wa2  = (const float*)d_in[11];
    const float* ba2  = (const float*)d_in[12];
    const float* Wa3  = (const float*)d_in[13];
    const float* ba3  = (const float*)d_in[14];
    const float* Wf_ih = (const float*)d_in[15];
    const float* Wf_hh = (const float*)d_in[16];
    const float* bf_ih = (const float*)d_in[17];
    const float* bf_hh = (const float*)d_in[18];
    const float* Wb_ih = (const float*)d_in[19];
    const float* Wb_hh = (const float*)d_in[20];
    const float* bb_ih = (const float*)d_in[21];
    const float* bb_hh = (const float*)d_in[22];
    const float* W3   = (const float*)d_in[23];
    const float* b3   = (const float*)d_in[24];
    const float* gg3  = (const float*)d_in[25];
    const float* be3  = (const float*)d_in[26];
    const float* W4   = (const float*)d_in[27];
    const float* b4   = (const float*)d_in[28];
    const float* gg4  = (const float*)d_in[29];
    const float* be4  = (const float*)d_in[30];

    float* out     = (float*)d_out;
    float* out_acts = out;                   // 128*128*64
    float* out_C    = out + 1048576;         // 128*128*128
    float* out_ip   = out + 3145728;         // 16384
    float* out_ii   = out + 3162112;         // 16384
    float* out_nt   = out + 3178496;         // 128*128*256 (evolving thoughts)
    float* out_ot   = out + 7372800;         // 128*128*256 (old thoughts)

    float* ws    = (float*)d_ws;
    float* h1    = ws;                               // 4194304
    float* abuf  = ws + 4194304;                     // 2097152 (a1, later dot)
    float* a2buf = ws + 6291456;                     // 2097152 (a2, later act-pre)
    unsigned short* wihbf = (unsigned short*)(ws + 8388608);  // 262144 shorts
    float* biasz = ws + 8519680;                     // 1024
    unsigned short* whhbf = (unsigned short*)(ws + 8520704);  // 131072 shorts
    float* sqb   = ws + 8586240;                     // 16384
    int* idxb    = (int*)(ws + 8602624);             // 262144
    int* flagsb  = (int*)(ws + 8864768);             // 16384

    prep_kernel<<<512, 256, 0, stream>>>(Wf_ih, Wb_ih, Wf_hh, Wb_hh,
                                         bf_ih, bf_hh, bb_ih, bb_hh,
                                         wihbf, whhbf, biasz);

    // actor_1
    gemm64<<<dim3(4, 256), 256, 0, stream>>>(obs, W1, b1, h1, 16384, 256, 512, 0);
    ln256_kernel<<<4096, 256, 0, stream>>>(h1, h1, nullptr, gg1, be1, 1);
    gemm64<<<dim3(4, 256), 256, 0, stream>>>(h1, W2, b2, out_nt, 16384, 256, 256, 0);
    ln256_kernel<<<4096, 256, 0, stream>>>(out_nt, out_nt, out_ot, gg2, be2, 0);

    // attention unit
    gemm64<<<dim3(2, 256), 256, 0, stream>>>(out_nt, Wa1, ba1, abuf, 16384, 128, 256, 1);
    gemm64<<<dim3(2, 256), 256, 0, stream>>>(abuf, Wa2, ba2, a2buf, 16384, 128, 128, 1);
    attn_head_kernel<<<4096, 256, 0, stream>>>(a2buf, Wa3, ba3, out_ip, out_ii, flagsb);

    // pairwise distances + top-16
    dot_kernel<<<256, 256, 0, stream>>>(out_nt, abuf);
    sq_kernel<<<64, 256, 0, stream>>>(abuf, sqb);
    topk_kernel<<<4096, 256, 0, stream>>>(abuf, sqb, flagsb, out_C, idxb);

    // sequential communication chain (mutates out_nt), all-LDS agent loop
    chain_kernel<<<128, 1024, 0, stream>>>(out_nt, whhbf, wihbf, biasz, idxb, flagsb);

    // actor_2
    gemm64<<<dim3(4, 256), 256, 0, stream>>>(out_nt, W3, b3, h1, 16384, 256, 256, 2);
    ln256_kernel<<<4096, 256, 0, stream>>>(h1, h1, nullptr, gg3, be3, 0);
    gemm64<<<dim3(1, 256), 256, 0, stream>>>(h1, W4, b4, a2buf, 16384, 64, 256, 0);
    ln64_tanh_kernel<<<4096, 256, 0, stream>>>(a2buf, out_acts, gg4, be4);
}

// Round 6
// 3730.355 us; speedup vs baseline: 1.3376x; 1.0634x over previous
//
#include <hip/hip_runtime.h>
#include <math.h>

typedef __attribute__((ext_vector_type(8))) short bf16x8;
typedef __attribute__((ext_vector_type(4))) float f32x4;

__device__ __forceinline__ unsigned short f2bf(float x) {
    unsigned int u = __float_as_uint(x);
    u += 0x7fffu + ((u >> 16) & 1u);
    return (unsigned short)(u >> 16);
}
__device__ __forceinline__ float bf2f(unsigned short b) {
    return __uint_as_float(((unsigned int)b) << 16);
}
// fast activations: v_exp_f32 + v_rcp_f32 (rel err ~1e-7, far below bf16 noise)
__device__ __forceinline__ float fsig(float z) {
    float e = __expf(-z);
    return __builtin_amdgcn_rcpf(1.f + e);
}
__device__ __forceinline__ float ftanh(float x) {
    float ax = fabsf(x);
    float e = __expf(-2.f * ax);
    float r = (1.f - e) * __builtin_amdgcn_rcpf(1.f + e);
    return copysignf(r, x);
}
__device__ __forceinline__ bf16x8 pack8(float4 a, float4 b) {
    bf16x8 r;
    r[0] = (short)f2bf(a.x); r[1] = (short)f2bf(a.y);
    r[2] = (short)f2bf(a.z); r[3] = (short)f2bf(a.w);
    r[4] = (short)f2bf(b.x); r[5] = (short)f2bf(b.y);
    r[6] = (short)f2bf(b.z); r[7] = (short)f2bf(b.w);
    return r;
}

// ---------------------------------------------------------------------------
// prep: convert Wih and Whh to bf16, bias sums
// ---------------------------------------------------------------------------
__global__ void prep_kernel(const float* __restrict__ Wf_ih, const float* __restrict__ Wb_ih,
                            const float* __restrict__ Wf_hh, const float* __restrict__ Wb_hh,
                            const float* __restrict__ bf_ih, const float* __restrict__ bf_hh,
                            const float* __restrict__ bb_ih, const float* __restrict__ bb_hh,
                            unsigned short* __restrict__ wihbf,
                            unsigned short* __restrict__ whhbf,
                            float* __restrict__ biasz) {
    int i = blockIdx.x * 256 + threadIdx.x;   // grid 512*256 = 131072
    if (i < 131072) {
        wihbf[i]          = f2bf(Wf_ih[i]);
        wihbf[131072 + i] = f2bf(Wb_ih[i]);
    }
    if (i < 65536) {
        whhbf[i]         = f2bf(Wf_hh[i]);
        whhbf[65536 + i] = f2bf(Wb_hh[i]);
    }
    if (i < 512) {
        biasz[i]       = bf_ih[i] + bf_hh[i];
        biasz[512 + i] = bb_ih[i] + bb_hh[i];
    }
}

// ---------------------------------------------------------------------------
// generic fp32 GEMM  C[M,N] = A[M,K] @ B[K,N] + bias ; flags: 1=relu_out 2=relu_A
// ---------------------------------------------------------------------------
__global__ __launch_bounds__(256) void gemm64(const float* __restrict__ A,
                                              const float* __restrict__ Bm,
                                              const float* __restrict__ bias,
                                              float* __restrict__ C,
                                              int M, int N, int K, int flags) {
    __shared__ float As[16][68];
    __shared__ float Bs[16][68];
    const int t = threadIdx.x;
    const int row0 = blockIdx.y * 64, col0 = blockIdx.x * 64;
    const int tm = t >> 4, tn = t & 15;
    float acc[4][4] = {};
    for (int k0 = 0; k0 < K; k0 += 16) {
        {
            int r = t >> 2, kq = (t & 3) * 4;
            float4 v = *(const float4*)(A + (size_t)(row0 + r) * K + k0 + kq);
            if (flags & 2) {
                v.x = fmaxf(v.x, 0.f); v.y = fmaxf(v.y, 0.f);
                v.z = fmaxf(v.z, 0.f); v.w = fmaxf(v.w, 0.f);
            }
            As[kq + 0][r] = v.x; As[kq + 1][r] = v.y;
            As[kq + 2][r] = v.z; As[kq + 3][r] = v.w;
        }
        {
            int kk = t >> 4, nq = (t & 15) * 4;
            float4 v = *(const float4*)(Bm + (size_t)(k0 + kk) * N + col0 + nq);
            *(float4*)&Bs[kk][nq] = v;
        }
        __syncthreads();
#pragma unroll
        for (int kk = 0; kk < 16; ++kk) {
            float a[4], b[4];
#pragma unroll
            for (int i = 0; i < 4; ++i) a[i] = As[kk][tm * 4 + i];
#pragma unroll
            for (int j = 0; j < 4; ++j) b[j] = Bs[kk][tn * 4 + j];
#pragma unroll
            for (int i = 0; i < 4; ++i)
#pragma unroll
                for (int j = 0; j < 4; ++j) acc[i][j] = fmaf(a[i], b[j], acc[i][j]);
        }
        __syncthreads();
    }
#pragma unroll
    for (int i = 0; i < 4; ++i) {
#pragma unroll
        for (int j = 0; j < 4; ++j) {
            int col = col0 + tn * 4 + j;
            float v = acc[i][j] + (bias ? bias[col] : 0.f);
            if (flags & 1) v = fmaxf(v, 0.f);
            C[(size_t)(row0 + tm * 4 + i) * N + col] = v;
        }
    }
}

// ---------------------------------------------------------------------------
// LayerNorm over 256, one wave per row. Optional relu, optional dup output.
// ---------------------------------------------------------------------------
__global__ __launch_bounds__(256) void ln256_kernel(const float* __restrict__ X,
                                                    float* __restrict__ Y,
                                                    float* __restrict__ Y2,
                                                    const float* __restrict__ gam,
                                                    const float* __restrict__ bet,
                                                    int relu) {
#pragma clang fp contract(off)
    int row = blockIdx.x * 4 + (threadIdx.x >> 6);
    int l = threadIdx.x & 63;
    float4 x = *(const float4*)(X + (size_t)row * 256 + l * 4);
    float s = x.x + x.y + x.z + x.w;
#pragma unroll
    for (int d = 1; d < 64; d <<= 1) s += __shfl_xor(s, d);
    float mu = s * (1.f / 256.f);
    float d0 = x.x - mu, d1 = x.y - mu, d2 = x.z - mu, d3 = x.w - mu;
    float ss = d0 * d0 + d1 * d1 + d2 * d2 + d3 * d3;
#pragma unroll
    for (int d = 1; d < 64; d <<= 1) ss += __shfl_xor(ss, d);
    float var = ss * (1.f / 256.f);
    float sd = sqrtf(var + 1e-5f);
    float4 y;
    y.x = (d0 / sd) * gam[l * 4 + 0] + bet[l * 4 + 0];
    y.y = (d1 / sd) * gam[l * 4 + 1] + bet[l * 4 + 1];
    y.z = (d2 / sd) * gam[l * 4 + 2] + bet[l * 4 + 2];
    y.w = (d3 / sd) * gam[l * 4 + 3] + bet[l * 4 + 3];
    if (relu) {
        y.x = fmaxf(y.x, 0.f); y.y = fmaxf(y.y, 0.f);
        y.z = fmaxf(y.z, 0.f); y.w = fmaxf(y.w, 0.f);
    }
    *(float4*)(Y + (size_t)row * 256 + l * 4) = y;
    if (Y2) *(float4*)(Y2 + (size_t)row * 256 + l * 4) = y;
}

// LayerNorm over 64 + tanh, one wave per row
__global__ __launch_bounds__(256) void ln64_tanh_kernel(const float* __restrict__ X,
                                                        float* __restrict__ Y,
                                                        const float* __restrict__ gam,
                                                        const float* __restrict__ bet) {
#pragma clang fp contract(off)
    int row = blockIdx.x * 4 + (threadIdx.x >> 6);
    int l = threadIdx.x & 63;
    float x = X[(size_t)row * 64 + l];
    float s = x;
#pragma unroll
    for (int d = 1; d < 64; d <<= 1) s += __shfl_xor(s, d);
    float mu = s * (1.f / 64.f);
    float dx = x - mu;
    float ss = dx * dx;
#pragma unroll
    for (int d = 1; d < 64; d <<= 1) ss += __shfl_xor(ss, d);
    float var = ss * (1.f / 64.f);
    float sd = sqrtf(var + 1e-5f);
    float y = tanhf((dx / sd) * gam[l] + bet[l]);
    Y[(size_t)row * 64 + l] = y;
}

// ---------------------------------------------------------------------------
// attention head: p = sigmoid(a2 @ Wa3 + ba3), flags = p > 0.4
// ---------------------------------------------------------------------------
__global__ __launch_bounds__(256) void attn_head_kernel(const float* __restrict__ a2,
                                                        const float* __restrict__ Wa3,
                                                        const float* __restrict__ ba3,
                                                        float* __restrict__ outP,
                                                        float* __restrict__ outInit,
                                                        int* __restrict__ flags) {
#pragma clang fp contract(off)
    int row = blockIdx.x * 4 + (threadIdx.x >> 6);
    int l = threadIdx.x & 63;
    float s = a2[(size_t)row * 128 + l] * Wa3[l] + a2[(size_t)row * 128 + 64 + l] * Wa3[64 + l];
#pragma unroll
    for (int d = 1; d < 64; d <<= 1) s += __shfl_xor(s, d);
    s += ba3[0];
    float p = 1.f / (1.f + expf(-s));
    if (l == 0) {
        outP[row] = p;
        int f = (p > 0.4f) ? 1 : 0;
        outInit[row] = f ? 1.f : 0.f;
        flags[row] = f;
    }
}

// ---------------------------------------------------------------------------
// batched dot: dot[b] = th_b @ th_b^T   (128x128, K=256); 2 blocks per batch
// ---------------------------------------------------------------------------
__global__ __launch_bounds__(256) void dot_kernel(const float* __restrict__ th,
                                                  float* __restrict__ dotm) {
    __shared__ float As[16][68];
    __shared__ float Bs[16][132];
    const int b = blockIdx.x >> 1, half = blockIdx.x & 1;
    const int t = threadIdx.x;
    const int tm = t >> 4, tn = t & 15;
    float acc[4][8] = {};
    const float* base = th + (size_t)b * 128 * 256;
    for (int k0 = 0; k0 < 256; k0 += 16) {
        {
            int r = t >> 2, kq = (t & 3) * 4;
            float4 v = *(const float4*)(base + (size_t)(half * 64 + r) * 256 + k0 + kq);
            As[kq + 0][r] = v.x; As[kq + 1][r] = v.y;
            As[kq + 2][r] = v.z; As[kq + 3][r] = v.w;
        }
        {
            int n = t >> 1, kq = (t & 1) * 8;
            const float* src = base + (size_t)n * 256 + k0 + kq;
            float4 v0 = *(const float4*)src;
            float4 v1 = *(const float4*)(src + 4);
            Bs[kq + 0][n] = v0.x; Bs[kq + 1][n] = v0.y;
            Bs[kq + 2][n] = v0.z; Bs[kq + 3][n] = v0.w;
            Bs[kq + 4][n] = v1.x; Bs[kq + 5][n] = v1.y;
            Bs[kq + 6][n] = v1.z; Bs[kq + 7][n] = v1.w;
        }
        __syncthreads();
#pragma unroll
        for (int kk = 0; kk < 16; ++kk) {
            float a[4], bb[8];
#pragma unroll
            for (int i = 0; i < 4; ++i) a[i] = As[kk][tm * 4 + i];
#pragma unroll
            for (int j = 0; j < 8; ++j) bb[j] = Bs[kk][tn * 8 + j];
#pragma unroll
            for (int i = 0; i < 4; ++i)
#pragma unroll
                for (int j = 0; j < 8; ++j) acc[i][j] = fmaf(a[i], bb[j], acc[i][j]);
        }
        __syncthreads();
    }
#pragma unroll
    for (int i = 0; i < 4; ++i)
#pragma unroll
        for (int j = 0; j < 8; ++j)
            dotm[(size_t)b * 16384 + (size_t)(half * 64 + tm * 4 + i) * 128 + tn * 8 + j] = acc[i][j];
}

__global__ void sq_kernel(const float* __restrict__ dotm, float* __restrict__ sq) {
    int i = blockIdx.x * 256 + threadIdx.x;   // 64 blocks
    int b = i >> 7, n = i & 127;
    sq[i] = dotm[(size_t)b * 16384 + (size_t)n * 129];
}

// ---------------------------------------------------------------------------
// top-16 smallest distances per row (ties -> lower index), write C + idx
// ---------------------------------------------------------------------------
__global__ __launch_bounds__(256) void topk_kernel(const float* __restrict__ dotm,
                                                   const float* __restrict__ sq,
                                                   const int* __restrict__ flags,
                                                   float* __restrict__ outC,
                                                   int* __restrict__ idxb) {
#pragma clang fp contract(off)
    int row = blockIdx.x * 4 + (threadIdx.x >> 6);
    int l = threadIdx.x & 63;
    int b = row >> 7;
    const float* drow = dotm + (size_t)row * 128;
    float sqi = sq[row];
    float t0 = 2.f * drow[l];
    float v0 = sq[b * 128 + l] - t0; v0 = v0 + sqi;
    float t1 = 2.f * drow[64 + l];
    float v1 = sq[b * 128 + 64 + l] - t1; v1 = v1 + sqi;

    unsigned long long mlo = 0ull, mhi = 0ull;
#pragma unroll 1
    for (int n = 0; n < 16; ++n) {
        float bv = v0; int bi = l;
        if (v1 < bv) { bv = v1; bi = 64 + l; }
#pragma unroll
        for (int d = 1; d < 64; d <<= 1) {
            float ov = __shfl_xor(bv, d);
            int oi = __shfl_xor(bi, d);
            if (ov < bv || (ov == bv && oi < bi)) { bv = ov; bi = oi; }
        }
        if (bi < 64) mlo |= (1ull << bi); else mhi |= (1ull << (bi - 64));
        if (l == bi) v0 = __builtin_inff();
        if (64 + l == bi) v1 = __builtin_inff();
    }
    float fl = (flags[row] != 0) ? 1.f : 0.f;
    outC[(size_t)row * 128 + l]      = fl * (((mlo >> l) & 1ull) ? 1.f : 0.f);
    outC[(size_t)row * 128 + 64 + l] = fl * (((mhi >> l) & 1ull) ? 1.f : 0.f);
    if (l < 16) {
        int cnt = 0, found = -1;
        for (int jj = 0; jj < 128; ++jj) {
            bool bit = (jj < 64) ? ((mlo >> jj) & 1ull) : ((mhi >> (jj - 64)) & 1ull);
            if (bit) { if (cnt == l) { found = jj; break; } ++cnt; }
        }
        idxb[(size_t)row * 16 + l] = found;
    }
}

// ---------------------------------------------------------------------------
// THE CHAIN: one 512-thread block per batch, 8 waves (4 fwd, 4 bwd), 2/SIMD.
// Wave wd of a dir owns 32 hidden units {wd*32 + hf*16 + lr}; Whh resident
// as 32 bf16x8 fragments = 128 VGPRs (launch_bounds(512,2) -> 256 cap, no
// spill). th slice lives in LDS bf16 (swizzled). Per-step LDS is minimal:
// 4x b128 (h) + 1x b128 (xg, [dir][wd][m][lr][8] lane-aligned layout) reads,
// 4x u16 writes, ONE 8-wave barrier. thl scatter deferred to agent end.
// ---------------------------------------------------------------------------
__global__ __launch_bounds__(512, 2) void chain_kernel(float* __restrict__ th,
                                                       const unsigned short* __restrict__ whhbf,
                                                       const unsigned short* __restrict__ wihbf,
                                                       const float* __restrict__ biasz,
                                                       const int* __restrict__ idxb,
                                                       const int* __restrict__ flags) {
    const int b = blockIdx.x;
    const int t = threadIdx.x;
    const int l = t & 63, lr = l & 15, lg = l >> 4;
    const int w = t >> 6, dir = w >> 2, wd = w & 3;

    __shared__ __align__(16) unsigned short thl[128 * 256];        // 64 KB swizzled bf16
    __shared__ __align__(16) unsigned short xgs2[2 * 4 * 16 * 16 * 8]; // 32 KB [dir][wd][m][lr][8]
    __shared__ __align__(16) unsigned short hsnap[2][16][128];     // 8 KB per-member h
    __shared__ __align__(16) unsigned short hbufs[2][2][128];      // 1 KB ping-pong h
    __shared__ int idxl[2048];                                     // 8 KB
    __shared__ int flg[128];

    // ---- load th slice -> bf16 LDS (swizzled); row r = t>>2, 64 floats each
    {
        int r = t >> 2, c0 = (t & 3) * 64;
        const float* src = th + (size_t)(b * 128 + r) * 256 + c0;
        char* rowb = (char*)thl + r * 512;
        int swz = (r & 7) << 4;
#pragma unroll
        for (int i = 0; i < 8; ++i) {
            float4 v0 = *(const float4*)(src + i * 8);
            float4 v1 = *(const float4*)(src + i * 8 + 4);
            *(bf16x8*)(rowb + (((c0 + i * 8) * 2) ^ swz)) = pack8(v0, v1);
        }
    }
    if (t < 128) flg[t] = flags[b * 128 + t];
#pragma unroll
    for (int c = 0; c < 4; ++c) idxl[t + c * 512] = idxb[(size_t)b * 2048 + c * 512 + t];

    // ---- resident Whh bf16 B-fragments: 32 frags = 128 VGPRs
    bf16x8 wf[4][2][4];
    {
        const unsigned short* whh = whhbf + (size_t)dir * 65536;
#pragma unroll
        for (int G = 0; G < 4; ++G)
#pragma unroll
            for (int hf = 0; hf < 2; ++hf) {
                int gate = G * 128 + wd * 32 + hf * 16 + lr;
#pragma unroll
                for (int kc = 0; kc < 4; ++kc)
                    wf[G][hf][kc] = *(const bf16x8*)(whh + (size_t)gate * 128 + kc * 32 + lg * 8);
            }
    }
    const unsigned short* wih = wihbf + (size_t)dir * 131072;
    float bzr[8];
#pragma unroll
    for (int tt = 0; tt < 8; ++tt)
        bzr[tt] = biasz[dir * 512 + (tt >> 1) * 128 + wd * 32 + (tt & 1) * 16 + lr];
    __syncthreads();

    for (int ag = 0; ag < 128; ++ag) {
        if (!flg[ag]) continue;
        const int gi_lr = idxl[ag * 16 + lr];
        const int xgbase = ((dir * 4 + wd) * 16) * 16 * 8;   // this wave's xg slab

        ((unsigned short*)hbufs)[t] = 0;   // zero both h ping-buffers (512 shorts)

        // xg: A rows = 16 members (thl rows gi), B cols = this wave's 8 gate
        // tiles tt=(G,hf); gate = G*128 + wd*32 + hf*16 + lr
        {
            f32x4 xa[8];
#pragma unroll
            for (int tt = 0; tt < 8; ++tt) xa[tt] = (f32x4){0.f, 0.f, 0.f, 0.f};
            const char* arow = (const char*)thl + gi_lr * 512;
            const int aswz = (gi_lr & 7) << 4;
#pragma unroll
            for (int kc = 0; kc < 8; ++kc) {
                bf16x8 af = *(const bf16x8*)(arow + ((kc * 64 + lg * 16) ^ aswz));
#pragma unroll
                for (int tt = 0; tt < 8; ++tt) {
                    const unsigned short* wb =
                        wih + (size_t)((tt >> 1) * 128 + wd * 32 + (tt & 1) * 16 + lr) * 256 +
                        kc * 32 + lg * 8;
                    xa[tt] = __builtin_amdgcn_mfma_f32_16x16x32_bf16(
                        af, *(const bf16x8*)wb, xa[tt], 0, 0, 0);
                }
            }
            // store transposed: [dir][wd][m][lr][8 gates] -> one b128 per (m,lr)
#pragma unroll
            for (int r = 0; r < 4; ++r) {
                bf16x8 pk;
#pragma unroll
                for (int tt = 0; tt < 8; ++tt) pk[tt] = (short)f2bf(xa[tt][r] + bzr[tt]);
                int m = lg * 4 + r;
                *(bf16x8*)&xgs2[xgbase + (m * 16 + lr) * 8] = pk;
            }
        }
        __syncthreads();   // xgs2 + hbuf zero ready

        // 16-step recurrence: 5x ds_read_b128 + 32 MFMA + acts per wave-step
        float cst0 = 0.f, cst1 = 0.f;
#pragma unroll 2
        for (int s = 0; s < 16; ++s) {
            const int m = dir ? (15 - s) : s;
            const int p = s & 1;
            f32x4 acc[4][2];
#pragma unroll
            for (int G = 0; G < 4; ++G) {
                acc[G][0] = (f32x4){0.f, 0.f, 0.f, 0.f};
                acc[G][1] = (f32x4){0.f, 0.f, 0.f, 0.f};
            }
#pragma unroll
            for (int kc = 0; kc < 4; ++kc) {
                bf16x8 ha = *(const bf16x8*)(&hbufs[p][dir][kc * 32 + lg * 8]);
#pragma unroll
                for (int G = 0; G < 4; ++G) {
                    acc[G][0] = __builtin_amdgcn_mfma_f32_16x16x32_bf16(
                        ha, wf[G][0][kc], acc[G][0], 0, 0, 0);
                    acc[G][1] = __builtin_amdgcn_mfma_f32_16x16x32_bf16(
                        ha, wf[G][1][kc], acc[G][1], 0, 0, 0);
                }
            }
            bf16x8 xp = *(const bf16x8*)&xgs2[xgbase + (m * 16 + lr) * 8];
            float zi0 = acc[0][0][0] + bf2f((unsigned short)xp[0]);
            float zf0 = acc[1][0][0] + bf2f((unsigned short)xp[2]);
            float zg0 = acc[2][0][0] + bf2f((unsigned short)xp[4]);
            float zo0 = acc[3][0][0] + bf2f((unsigned short)xp[6]);
            float zi1 = acc[0][1][0] + bf2f((unsigned short)xp[1]);
            float zf1 = acc[1][1][0] + bf2f((unsigned short)xp[3]);
            float zg1 = acc[2][1][0] + bf2f((unsigned short)xp[5]);
            float zo1 = acc[3][1][0] + bf2f((unsigned short)xp[7]);
            float i0 = fsig(zi0), f0 = fsig(zf0), g0 = ftanh(zg0), o0 = fsig(zo0);
            cst0 = f0 * cst0 + i0 * g0;
            float h0 = o0 * ftanh(cst0);
            float i1 = fsig(zi1), f1 = fsig(zf1), g1 = ftanh(zg1), o1 = fsig(zo1);
            cst1 = f1 * cst1 + i1 * g1;
            float h1 = o1 * ftanh(cst1);
            if (lg == 0) {
                int j0 = wd * 32 + lr;
                unsigned short hb0 = f2bf(h0), hb1 = f2bf(h1);
                hbufs[p ^ 1][dir][j0]      = hb0;
                hbufs[p ^ 1][dir][j0 + 16] = hb1;
                hsnap[dir][m][j0]      = hb0;
                hsnap[dir][m][j0 + 16] = hb1;
            }
            __syncthreads();
        }

        // bulk scatter hsnap -> thl (swizzled), 512 threads cover 2*16*128
        {
            int d2 = t >> 8, m = (t >> 4) & 15, c8 = (t & 15) * 8;
            bf16x8 v = *(const bf16x8*)&hsnap[d2][m][c8];
            int row = idxl[ag * 16 + m];
            *(bf16x8*)((char*)thl + row * 512 + (((d2 * 128 + c8) * 2) ^ ((row & 7) << 4))) = v;
        }
        __syncthreads();
    }

    // ---- write back the whole slice (un-swizzle, bf16 -> fp32)
    {
        int r = t >> 2, c0 = (t & 3) * 64;
        const char* rowb = (const char*)thl + r * 512;
        int swz = (r & 7) << 4;
        float* dst = th + (size_t)(b * 128 + r) * 256 + c0;
#pragma unroll
        for (int i = 0; i < 8; ++i) {
            bf16x8 sv = *(const bf16x8*)(rowb + (((c0 + i * 8) * 2) ^ swz));
            float4 v0, v1;
            v0.x = bf2f((unsigned short)sv[0]); v0.y = bf2f((unsigned short)sv[1]);
            v0.z = bf2f((unsigned short)sv[2]); v0.w = bf2f((unsigned short)sv[3]);
            v1.x = bf2f((unsigned short)sv[4]); v1.y = bf2f((unsigned short)sv[5]);
            v1.z = bf2f((unsigned short)sv[6]); v1.w = bf2f((unsigned short)sv[7]);
            *(float4*)(dst + i * 8) = v0;
            *(float4*)(dst + i * 8 + 4) = v1;
        }
    }
}

// ---------------------------------------------------------------------------
extern "C" void kernel_launch(void* const* d_in, const int* in_sizes, int n_in,
                              void* d_out, int out_size, void* d_ws, size_t ws_size,
                              hipStream_t stream) {
    const float* obs  = (const float*)d_in[0];
    const float* W1   = (const float*)d_in[1];
    const float* b1   = (const float*)d_in[2];
    const float* gg1  = (const float*)d_in[3];
    const float* be1  = (const float*)d_in[4];
    const float* W2   = (const float*)d_in[5];
    const float* b2   = (const float*)d_in[6];
    const float* gg2  = (const float*)d_in[7];
    const float* be2  = (const float*)d_in[8];
    const float* Wa1  = (const float*)d_in[9];
    const float* ba1  = (const float*)d_in[10];
    const float* Wa2  = (const float*)d_in[11];
    const float* ba2  = (const float*)d_in[12];
    const float* Wa3  = (const float*)d_in[13];
    const float* ba3  = (const float*)d_in[14];
    const float* Wf_ih = (const float*)d_in[15];
    const float* Wf_hh = (const float*)d_in[16];
    const float* bf_ih = (const float*)d_in[17];
    const float* bf_hh = (const float*)d_in[18];
    const float* Wb_ih = (const float*)d_in[19];
    const float* Wb_hh = (const float*)d_in[20];
    const float* bb_ih = (const float*)d_in[21];
    const float* bb_hh = (const float*)d_in[22];
    const float* W3   = (const float*)d_in[23];
    const float* b3   = (const float*)d_in[24];
    const float* gg3  = (const float*)d_in[25];
    const float* be3  = (const float*)d_in[26];
    const float* W4   = (const float*)d_in[27];
    const float* b4   = (const float*)d_in[28];
    const float* gg4  = (const float*)d_in[29];
    const float* be4  = (const float*)d_in[30];

    float* out     = (float*)d_out;
    float* out_acts = out;                   // 128*128*64
    float* out_C    = out + 1048576;         // 128*128*128
    float* out_ip   = out + 3145728;         // 16384
    float* out_ii   = out + 3162112;         // 16384
    float* out_nt   = out + 3178496;         // 128*128*256 (evolving thoughts)
    float* out_ot   = out + 7372800;         // 128*128*256 (old thoughts)

    float* ws    = (float*)d_ws;
    float* h1    = ws;                               // 4194304
    float* abuf  = ws + 4194304;                     // 2097152 (a1, later dot)
    float* a2buf = ws + 6291456;                     // 2097152 (a2, later act-pre)
    unsigned short* wihbf = (unsigned short*)(ws + 8388608);  // 262144 shorts
    float* biasz = ws + 8519680;                     // 1024
    unsigned short* whhbf = (unsigned short*)(ws + 8520704);  // 131072 shorts
    float* sqb   = ws + 8586240;                     // 16384
    int* idxb    = (int*)(ws + 8602624);             // 262144
    int* flagsb  = (int*)(ws + 8864768);             // 16384

    prep_kernel<<<512, 256, 0, stream>>>(Wf_ih, Wb_ih, Wf_hh, Wb_hh,
                                         bf_ih, bf_hh, bb_ih, bb_hh,
                                         wihbf, whhbf, biasz);

    // actor_1
    gemm64<<<dim3(4, 256), 256, 0, stream>>>(obs, W1, b1, h1, 16384, 256, 512, 0);
    ln256_kernel<<<4096, 256, 0, stream>>>(h1, h1, nullptr, gg1, be1, 1);
    gemm64<<<dim3(4, 256), 256, 0, stream>>>(h1, W2, b2, out_nt, 16384, 256, 256, 0);
    ln256_kernel<<<4096, 256, 0, stream>>>(out_nt, out_nt, out_ot, gg2, be2, 0);

    // attention unit
    gemm64<<<dim3(2, 256), 256, 0, stream>>>(out_nt, Wa1, ba1, abuf, 16384, 128, 256, 1);
    gemm64<<<dim3(2, 256), 256, 0, stream>>>(abuf, Wa2, ba2, a2buf, 16384, 128, 128, 1);
    attn_head_kernel<<<4096, 256, 0, stream>>>(a2buf, Wa3, ba3, out_ip, out_ii, flagsb);

    // pairwise distances + top-16
    dot_kernel<<<256, 256, 0, stream>>>(out_nt, abuf);
    sq_kernel<<<64, 256, 0, stream>>>(abuf, sqb);
    topk_kernel<<<4096, 256, 0, stream>>>(abuf, sqb, flagsb, out_C, idxb);

    // sequential communication chain (mutates out_nt), all-LDS agent loop
    chain_kernel<<<128, 512, 0, stream>>>(out_nt, whhbf, wihbf, biasz, idxb, flagsb);

    // actor_2
    gemm64<<<dim3(4, 256), 256, 0, stream>>>(out_nt, W3, b3, h1, 16384, 256, 256, 2);
    ln256_kernel<<<4096, 256, 0, stream>>>(h1, h1, nullptr, gg3, be3, 0);
    gemm64<<<dim3(1, 256), 256, 0, stream>>>(h1, W4, b4, a2buf, 16384, 64, 256, 0);
    ln64_tanh_kernel<<<4096, 256, 0, stream>>>(a2buf, out_acts, gg4, be4);
}

// Round 7
// 3611.848 us; speedup vs baseline: 1.3815x; 1.0328x over previous
//
#include <hip/hip_runtime.h>
#include <math.h>

typedef __attribute__((ext_vector_type(8))) short bf16x8;
typedef __attribute__((ext_vector_type(4))) float f32x4;

__device__ __forceinline__ unsigned short f2bf(float x) {
    unsigned int u = __float_as_uint(x);
    u += 0x7fffu + ((u >> 16) & 1u);
    return (unsigned short)(u >> 16);
}
__device__ __forceinline__ float bf2f(unsigned short b) {
    return __uint_as_float(((unsigned int)b) << 16);
}
// fast activations: v_exp_f32 + v_rcp_f32 (rel err ~1e-7, far below bf16 noise)
__device__ __forceinline__ float fsig(float z) {
    float e = __expf(-z);
    return __builtin_amdgcn_rcpf(1.f + e);
}
// tanh(x) = 2*sigmoid(2x) - 1  (5 instrs)
__device__ __forceinline__ float ftanh(float x) {
    float e = __expf(-2.f * x);
    float s = __builtin_amdgcn_rcpf(1.f + e);
    return fmaf(2.f, s, -1.f);
}
__device__ __forceinline__ bf16x8 pack8(float4 a, float4 b) {
    bf16x8 r;
    r[0] = (short)f2bf(a.x); r[1] = (short)f2bf(a.y);
    r[2] = (short)f2bf(a.z); r[3] = (short)f2bf(a.w);
    r[4] = (short)f2bf(b.x); r[5] = (short)f2bf(b.y);
    r[6] = (short)f2bf(b.z); r[7] = (short)f2bf(b.w);
    return r;
}

// ---------------------------------------------------------------------------
// prep: convert Wih and Whh to bf16, bias sums
// ---------------------------------------------------------------------------
__global__ void prep_kernel(const float* __restrict__ Wf_ih, const float* __restrict__ Wb_ih,
                            const float* __restrict__ Wf_hh, const float* __restrict__ Wb_hh,
                            const float* __restrict__ bf_ih, const float* __restrict__ bf_hh,
                            const float* __restrict__ bb_ih, const float* __restrict__ bb_hh,
                            unsigned short* __restrict__ wihbf,
                            unsigned short* __restrict__ whhbf,
                            float* __restrict__ biasz) {
    int i = blockIdx.x * 256 + threadIdx.x;   // grid 512*256 = 131072
    if (i < 131072) {
        wihbf[i]          = f2bf(Wf_ih[i]);
        wihbf[131072 + i] = f2bf(Wb_ih[i]);
    }
    if (i < 65536) {
        whhbf[i]         = f2bf(Wf_hh[i]);
        whhbf[65536 + i] = f2bf(Wb_hh[i]);
    }
    if (i < 512) {
        biasz[i]       = bf_ih[i] + bf_hh[i];
        biasz[512 + i] = bb_ih[i] + bb_hh[i];
    }
}

// ---------------------------------------------------------------------------
// generic fp32 GEMM  C[M,N] = A[M,K] @ B[K,N] + bias ; flags: 1=relu_out 2=relu_A
// ---------------------------------------------------------------------------
__global__ __launch_bounds__(256) void gemm64(const float* __restrict__ A,
                                              const float* __restrict__ Bm,
                                              const float* __restrict__ bias,
                                              float* __restrict__ C,
                                              int M, int N, int K, int flags) {
    __shared__ float As[16][68];
    __shared__ float Bs[16][68];
    const int t = threadIdx.x;
    const int row0 = blockIdx.y * 64, col0 = blockIdx.x * 64;
    const int tm = t >> 4, tn = t & 15;
    float acc[4][4] = {};
    for (int k0 = 0; k0 < K; k0 += 16) {
        {
            int r = t >> 2, kq = (t & 3) * 4;
            float4 v = *(const float4*)(A + (size_t)(row0 + r) * K + k0 + kq);
            if (flags & 2) {
                v.x = fmaxf(v.x, 0.f); v.y = fmaxf(v.y, 0.f);
                v.z = fmaxf(v.z, 0.f); v.w = fmaxf(v.w, 0.f);
            }
            As[kq + 0][r] = v.x; As[kq + 1][r] = v.y;
            As[kq + 2][r] = v.z; As[kq + 3][r] = v.w;
        }
        {
            int kk = t >> 4, nq = (t & 15) * 4;
            float4 v = *(const float4*)(Bm + (size_t)(k0 + kk) * N + col0 + nq);
            *(float4*)&Bs[kk][nq] = v;
        }
        __syncthreads();
#pragma unroll
        for (int kk = 0; kk < 16; ++kk) {
            float a[4], b[4];
#pragma unroll
            for (int i = 0; i < 4; ++i) a[i] = As[kk][tm * 4 + i];
#pragma unroll
            for (int j = 0; j < 4; ++j) b[j] = Bs[kk][tn * 4 + j];
#pragma unroll
            for (int i = 0; i < 4; ++i)
#pragma unroll
                for (int j = 0; j < 4; ++j) acc[i][j] = fmaf(a[i], b[j], acc[i][j]);
        }
        __syncthreads();
    }
#pragma unroll
    for (int i = 0; i < 4; ++i) {
#pragma unroll
        for (int j = 0; j < 4; ++j) {
            int col = col0 + tn * 4 + j;
            float v = acc[i][j] + (bias ? bias[col] : 0.f);
            if (flags & 1) v = fmaxf(v, 0.f);
            C[(size_t)(row0 + tm * 4 + i) * N + col] = v;
        }
    }
}

// ---------------------------------------------------------------------------
// LayerNorm over 256, one wave per row. Optional relu, optional dup output.
// ---------------------------------------------------------------------------
__global__ __launch_bounds__(256) void ln256_kernel(const float* __restrict__ X,
                                                    float* __restrict__ Y,
                                                    float* __restrict__ Y2,
                                                    const float* __restrict__ gam,
                                                    const float* __restrict__ bet,
                                                    int relu) {
#pragma clang fp contract(off)
    int row = blockIdx.x * 4 + (threadIdx.x >> 6);
    int l = threadIdx.x & 63;
    float4 x = *(const float4*)(X + (size_t)row * 256 + l * 4);
    float s = x.x + x.y + x.z + x.w;
#pragma unroll
    for (int d = 1; d < 64; d <<= 1) s += __shfl_xor(s, d);
    float mu = s * (1.f / 256.f);
    float d0 = x.x - mu, d1 = x.y - mu, d2 = x.z - mu, d3 = x.w - mu;
    float ss = d0 * d0 + d1 * d1 + d2 * d2 + d3 * d3;
#pragma unroll
    for (int d = 1; d < 64; d <<= 1) ss += __shfl_xor(ss, d);
    float var = ss * (1.f / 256.f);
    float sd = sqrtf(var + 1e-5f);
    float4 y;
    y.x = (d0 / sd) * gam[l * 4 + 0] + bet[l * 4 + 0];
    y.y = (d1 / sd) * gam[l * 4 + 1] + bet[l * 4 + 1];
    y.z = (d2 / sd) * gam[l * 4 + 2] + bet[l * 4 + 2];
    y.w = (d3 / sd) * gam[l * 4 + 3] + bet[l * 4 + 3];
    if (relu) {
        y.x = fmaxf(y.x, 0.f); y.y = fmaxf(y.y, 0.f);
        y.z = fmaxf(y.z, 0.f); y.w = fmaxf(y.w, 0.f);
    }
    *(float4*)(Y + (size_t)row * 256 + l * 4) = y;
    if (Y2) *(float4*)(Y2 + (size_t)row * 256 + l * 4) = y;
}

// LayerNorm over 64 + tanh, one wave per row
__global__ __launch_bounds__(256) void ln64_tanh_kernel(const float* __restrict__ X,
                                                        float* __restrict__ Y,
                                                        const float* __restrict__ gam,
                                                        const float* __restrict__ bet) {
#pragma clang fp contract(off)
    int row = blockIdx.x * 4 + (threadIdx.x >> 6);
    int l = threadIdx.x & 63;
    float x = X[(size_t)row * 64 + l];
    float s = x;
#pragma unroll
    for (int d = 1; d < 64; d <<= 1) s += __shfl_xor(s, d);
    float mu = s * (1.f / 64.f);
    float dx = x - mu;
    float ss = dx * dx;
#pragma unroll
    for (int d = 1; d < 64; d <<= 1) ss += __shfl_xor(ss, d);
    float var = ss * (1.f / 64.f);
    float sd = sqrtf(var + 1e-5f);
    float y = tanhf((dx / sd) * gam[l] + bet[l]);
    Y[(size_t)row * 64 + l] = y;
}

// ---------------------------------------------------------------------------
// attention head: p = sigmoid(a2 @ Wa3 + ba3), flags = p > 0.4
// ---------------------------------------------------------------------------
__global__ __launch_bounds__(256) void attn_head_kernel(const float* __restrict__ a2,
                                                        const float* __restrict__ Wa3,
                                                        const float* __restrict__ ba3,
                                                        float* __restrict__ outP,
                                                        float* __restrict__ outInit,
                                                        int* __restrict__ flags) {
#pragma clang fp contract(off)
    int row = blockIdx.x * 4 + (threadIdx.x >> 6);
    int l = threadIdx.x & 63;
    float s = a2[(size_t)row * 128 + l] * Wa3[l] + a2[(size_t)row * 128 + 64 + l] * Wa3[64 + l];
#pragma unroll
    for (int d = 1; d < 64; d <<= 1) s += __shfl_xor(s, d);
    s += ba3[0];
    float p = 1.f / (1.f + expf(-s));
    if (l == 0) {
        outP[row] = p;
        int f = (p > 0.4f) ? 1 : 0;
        outInit[row] = f ? 1.f : 0.f;
        flags[row] = f;
    }
}

// ---------------------------------------------------------------------------
// batched dot: dot[b] = th_b @ th_b^T   (128x128, K=256); 2 blocks per batch
// ---------------------------------------------------------------------------
__global__ __launch_bounds__(256) void dot_kernel(const float* __restrict__ th,
                                                  float* __restrict__ dotm) {
    __shared__ float As[16][68];
    __shared__ float Bs[16][132];
    const int b = blockIdx.x >> 1, half = blockIdx.x & 1;
    const int t = threadIdx.x;
    const int tm = t >> 4, tn = t & 15;
    float acc[4][8] = {};
    const float* base = th + (size_t)b * 128 * 256;
    for (int k0 = 0; k0 < 256; k0 += 16) {
        {
            int r = t >> 2, kq = (t & 3) * 4;
            float4 v = *(const float4*)(base + (size_t)(half * 64 + r) * 256 + k0 + kq);
            As[kq + 0][r] = v.x; As[kq + 1][r] = v.y;
            As[kq + 2][r] = v.z; As[kq + 3][r] = v.w;
        }
        {
            int n = t >> 1, kq = (t & 1) * 8;
            const float* src = base + (size_t)n * 256 + k0 + kq;
            float4 v0 = *(const float4*)src;
            float4 v1 = *(const float4*)(src + 4);
            Bs[kq + 0][n] = v0.x; Bs[kq + 1][n] = v0.y;
            Bs[kq + 2][n] = v0.z; Bs[kq + 3][n] = v0.w;
            Bs[kq + 4][n] = v1.x; Bs[kq + 5][n] = v1.y;
            Bs[kq + 6][n] = v1.z; Bs[kq + 7][n] = v1.w;
        }
        __syncthreads();
#pragma unroll
        for (int kk = 0; kk < 16; ++kk) {
            float a[4], bb[8];
#pragma unroll
            for (int i = 0; i < 4; ++i) a[i] = As[kk][tm * 4 + i];
#pragma unroll
            for (int j = 0; j < 8; ++j) bb[j] = Bs[kk][tn * 8 + j];
#pragma unroll
            for (int i = 0; i < 4; ++i)
#pragma unroll
                for (int j = 0; j < 8; ++j) acc[i][j] = fmaf(a[i], bb[j], acc[i][j]);
        }
        __syncthreads();
    }
#pragma unroll
    for (int i = 0; i < 4; ++i)
#pragma unroll
        for (int j = 0; j < 8; ++j)
            dotm[(size_t)b * 16384 + (size_t)(half * 64 + tm * 4 + i) * 128 + tn * 8 + j] = acc[i][j];
}

__global__ void sq_kernel(const float* __restrict__ dotm, float* __restrict__ sq) {
    int i = blockIdx.x * 256 + threadIdx.x;   // 64 blocks
    int b = i >> 7, n = i & 127;
    sq[i] = dotm[(size_t)b * 16384 + (size_t)n * 129];
}

// ---------------------------------------------------------------------------
// top-16 smallest distances per row (ties -> lower index), write C + idx
// ---------------------------------------------------------------------------
__global__ __launch_bounds__(256) void topk_kernel(const float* __restrict__ dotm,
                                                   const float* __restrict__ sq,
                                                   const int* __restrict__ flags,
                                                   float* __restrict__ outC,
                                                   int* __restrict__ idxb) {
#pragma clang fp contract(off)
    int row = blockIdx.x * 4 + (threadIdx.x >> 6);
    int l = threadIdx.x & 63;
    int b = row >> 7;
    const float* drow = dotm + (size_t)row * 128;
    float sqi = sq[row];
    float t0 = 2.f * drow[l];
    float v0 = sq[b * 128 + l] - t0; v0 = v0 + sqi;
    float t1 = 2.f * drow[64 + l];
    float v1 = sq[b * 128 + 64 + l] - t1; v1 = v1 + sqi;

    unsigned long long mlo = 0ull, mhi = 0ull;
#pragma unroll 1
    for (int n = 0; n < 16; ++n) {
        float bv = v0; int bi = l;
        if (v1 < bv) { bv = v1; bi = 64 + l; }
#pragma unroll
        for (int d = 1; d < 64; d <<= 1) {
            float ov = __shfl_xor(bv, d);
            int oi = __shfl_xor(bi, d);
            if (ov < bv || (ov == bv && oi < bi)) { bv = ov; bi = oi; }
        }
        if (bi < 64) mlo |= (1ull << bi); else mhi |= (1ull << (bi - 64));
        if (l == bi) v0 = __builtin_inff();
        if (64 + l == bi) v1 = __builtin_inff();
    }
    float fl = (flags[row] != 0) ? 1.f : 0.f;
    outC[(size_t)row * 128 + l]      = fl * (((mlo >> l) & 1ull) ? 1.f : 0.f);
    outC[(size_t)row * 128 + 64 + l] = fl * (((mhi >> l) & 1ull) ? 1.f : 0.f);
    if (l < 16) {
        int cnt = 0, found = -1;
        for (int jj = 0; jj < 128; ++jj) {
            bool bit = (jj < 64) ? ((mlo >> jj) & 1ull) : ((mhi >> (jj - 64)) & 1ull);
            if (bit) { if (cnt == l) { found = jj; break; } ++cnt; }
        }
        idxb[(size_t)row * 16 + l] = found;
    }
}

// ---------------------------------------------------------------------------
// THE CHAIN: one 512-thread block per batch, 8 waves (4 fwd, 4 bwd), 2/SIMD.
// Lane lr of wave wd owns ADJACENT units {wd*32+2lr, wd*32+2lr+1} (gate row
// = G*128 + wd*32 + 2lr + hf) -> one ds_write_b32 per step. h history lives
// in hsnap[2][18][128] (rows 0/17 = permanent zero initial state): the step
// reads prev-member h from row m (fwd) / m+2 (bwd) and writes row m+1 — no
// ping-pong, no per-agent zeroing. Whh resident: 32 bf16x8 = 128 VGPRs.
// Per-step LDS: 4x b128 (h) + 1x b128 (xg prefetch) reads + 1x b32 write,
// ONE barrier.
// ---------------------------------------------------------------------------
__global__ __launch_bounds__(512, 2) void chain_kernel(float* __restrict__ th,
                                                       const unsigned short* __restrict__ whhbf,
                                                       const unsigned short* __restrict__ wihbf,
                                                       const float* __restrict__ biasz,
                                                       const int* __restrict__ idxb,
                                                       const int* __restrict__ flags) {
    const int b = blockIdx.x;
    const int t = threadIdx.x;
    const int l = t & 63, lr = l & 15, lg = l >> 4;
    const int w = t >> 6, dir = w >> 2, wd = w & 3;

    __shared__ __align__(16) unsigned short thl[128 * 256];        // 64 KB swizzled bf16
    __shared__ __align__(16) unsigned short xgs2[2 * 4 * 16 * 16 * 8]; // 32 KB [dir][wd][m][lr][8]
    __shared__ __align__(16) unsigned short hsnap[2][18][128];     // 9 KB h history + 0-rows
    __shared__ int idxl[2048];                                     // 8 KB
    __shared__ int flg[128];

    // ---- load th slice -> bf16 LDS (swizzled); row r = t>>2, 64 floats each
    {
        int r = t >> 2, c0 = (t & 3) * 64;
        const float* src = th + (size_t)(b * 128 + r) * 256 + c0;
        char* rowb = (char*)thl + r * 512;
        int swz = (r & 7) << 4;
#pragma unroll
        for (int i = 0; i < 8; ++i) {
            float4 v0 = *(const float4*)(src + i * 8);
            float4 v1 = *(const float4*)(src + i * 8 + 4);
            *(bf16x8*)(rowb + (((c0 + i * 8) * 2) ^ swz)) = pack8(v0, v1);
        }
    }
    if (t < 128) flg[t] = flags[b * 128 + t];
    if (t < 256) {   // permanent zero boundary rows (initial LSTM state)
        int d2 = t >> 7, j = t & 127;
        hsnap[d2][0][j] = 0;
        hsnap[d2][17][j] = 0;
    }
#pragma unroll
    for (int c = 0; c < 4; ++c) idxl[t + c * 512] = idxb[(size_t)b * 2048 + c * 512 + t];

    // ---- resident Whh bf16 B-fragments: 32 frags = 128 VGPRs
    bf16x8 wf[4][2][4];
    {
        const unsigned short* whh = whhbf + (size_t)dir * 65536;
#pragma unroll
        for (int G = 0; G < 4; ++G)
#pragma unroll
            for (int hf = 0; hf < 2; ++hf) {
                int gate = G * 128 + wd * 32 + 2 * lr + hf;
#pragma unroll
                for (int kc = 0; kc < 4; ++kc)
                    wf[G][hf][kc] = *(const bf16x8*)(whh + (size_t)gate * 128 + kc * 32 + lg * 8);
            }
    }
    const unsigned short* wih = wihbf + (size_t)dir * 131072;
    float bzr[8];
#pragma unroll
    for (int tt = 0; tt < 8; ++tt)
        bzr[tt] = biasz[dir * 512 + (tt >> 1) * 128 + wd * 32 + 2 * lr + (tt & 1)];
    __syncthreads();

    for (int ag = 0; ag < 128; ++ag) {
        if (!flg[ag]) continue;
        const int gi_lr = idxl[ag * 16 + lr];
        const int xgbase = ((dir * 4 + wd) * 16) * 16 * 8;   // this wave's xg slab

        // xg: A rows = 16 members (thl rows gi), B cols = this wave's 8 gate
        // tiles tt=(G,hf); gate = G*128 + wd*32 + 2*lr + hf
        {
            f32x4 xa[8];
#pragma unroll
            for (int tt = 0; tt < 8; ++tt) xa[tt] = (f32x4){0.f, 0.f, 0.f, 0.f};
            const char* arow = (const char*)thl + gi_lr * 512;
            const int aswz = (gi_lr & 7) << 4;
#pragma unroll
            for (int kc = 0; kc < 8; ++kc) {
                bf16x8 af = *(const bf16x8*)(arow + ((kc * 64 + lg * 16) ^ aswz));
#pragma unroll
                for (int tt = 0; tt < 8; ++tt) {
                    const unsigned short* wb =
                        wih + (size_t)((tt >> 1) * 128 + wd * 32 + 2 * lr + (tt & 1)) * 256 +
                        kc * 32 + lg * 8;
                    xa[tt] = __builtin_amdgcn_mfma_f32_16x16x32_bf16(
                        af, *(const bf16x8*)wb, xa[tt], 0, 0, 0);
                }
            }
            // store transposed: [dir][wd][m][lr][8 gates] -> one b128 per (m,lr)
#pragma unroll
            for (int r = 0; r < 4; ++r) {
                bf16x8 pk;
#pragma unroll
                for (int tt = 0; tt < 8; ++tt) pk[tt] = (short)f2bf(xa[tt][r] + bzr[tt]);
                int m = lg * 4 + r;
                *(bf16x8*)&xgs2[xgbase + (m * 16 + lr) * 8] = pk;
            }
        }
        __syncthreads();   // xgs2 ready

        // preload xg for first step
        bf16x8 xpn = *(const bf16x8*)&xgs2[xgbase + ((dir ? 15 : 0) * 16 + lr) * 8];

        // 16-step recurrence: 5x ds_read_b128 + 16 MFMA + acts + 1x ds_write_b32
        float cst0 = 0.f, cst1 = 0.f;
        for (int s = 0; s < 16; ++s) {
            const int m = dir ? (15 - s) : s;
            const int rprev = dir ? (m + 2) : m;
            f32x4 acc[4][2];
#pragma unroll
            for (int G = 0; G < 4; ++G) {
                acc[G][0] = (f32x4){0.f, 0.f, 0.f, 0.f};
                acc[G][1] = (f32x4){0.f, 0.f, 0.f, 0.f};
            }
#pragma unroll
            for (int kc = 0; kc < 4; ++kc) {
                bf16x8 ha = *(const bf16x8*)(&hsnap[dir][rprev][kc * 32 + lg * 8]);
#pragma unroll
                for (int G = 0; G < 4; ++G) {
                    acc[G][0] = __builtin_amdgcn_mfma_f32_16x16x32_bf16(
                        ha, wf[G][0][kc], acc[G][0], 0, 0, 0);
                    acc[G][1] = __builtin_amdgcn_mfma_f32_16x16x32_bf16(
                        ha, wf[G][1][kc], acc[G][1], 0, 0, 0);
                }
            }
            bf16x8 xp = xpn;
            float zi0 = acc[0][0][0] + bf2f((unsigned short)xp[0]);
            float zi1 = acc[0][1][0] + bf2f((unsigned short)xp[1]);
            float zf0 = acc[1][0][0] + bf2f((unsigned short)xp[2]);
            float zf1 = acc[1][1][0] + bf2f((unsigned short)xp[3]);
            float zg0 = acc[2][0][0] + bf2f((unsigned short)xp[4]);
            float zg1 = acc[2][1][0] + bf2f((unsigned short)xp[5]);
            float zo0 = acc[3][0][0] + bf2f((unsigned short)xp[6]);
            float zo1 = acc[3][1][0] + bf2f((unsigned short)xp[7]);
            float i0 = fsig(zi0), f0 = fsig(zf0), g0 = ftanh(zg0), o0 = fsig(zo0);
            cst0 = f0 * cst0 + i0 * g0;
            float h0 = o0 * ftanh(cst0);
            float i1 = fsig(zi1), f1 = fsig(zf1), g1 = ftanh(zg1), o1 = fsig(zo1);
            cst1 = f1 * cst1 + i1 * g1;
            float h1 = o1 * ftanh(cst1);
            if (lg == 0) {
                unsigned int hw = (unsigned int)f2bf(h0) | ((unsigned int)f2bf(h1) << 16);
                *(unsigned int*)&hsnap[dir][m + 1][wd * 32 + 2 * lr] = hw;
            }
            // prefetch next step's xg (hides ds latency under barrier wait)
            if (s < 15) {
                int mn = dir ? (14 - s) : (s + 1);
                xpn = *(const bf16x8*)&xgs2[xgbase + (mn * 16 + lr) * 8];
            }
            __syncthreads();
        }

        // bulk scatter hsnap -> thl (swizzled), 512 threads cover 2*16*128
        {
            int d2 = t >> 8, m = (t >> 4) & 15, c8 = (t & 15) * 8;
            bf16x8 v = *(const bf16x8*)&hsnap[d2][m + 1][c8];
            int row = idxl[ag * 16 + m];
            *(bf16x8*)((char*)thl + row * 512 + (((d2 * 128 + c8) * 2) ^ ((row & 7) << 4))) = v;
        }
        __syncthreads();
    }

    // ---- write back the whole slice (un-swizzle, bf16 -> fp32)
    {
        int r = t >> 2, c0 = (t & 3) * 64;
        const char* rowb = (const char*)thl + r * 512;
        int swz = (r & 7) << 4;
        float* dst = th + (size_t)(b * 128 + r) * 256 + c0;
#pragma unroll
        for (int i = 0; i < 8; ++i) {
            bf16x8 sv = *(const bf16x8*)(rowb + (((c0 + i * 8) * 2) ^ swz));
            float4 v0, v1;
            v0.x = bf2f((unsigned short)sv[0]); v0.y = bf2f((unsigned short)sv[1]);
            v0.z = bf2f((unsigned short)sv[2]); v0.w = bf2f((unsigned short)sv[3]);
            v1.x = bf2f((unsigned short)sv[4]); v1.y = bf2f((unsigned short)sv[5]);
            v1.z = bf2f((unsigned short)sv[6]); v1.w = bf2f((unsigned short)sv[7]);
            *(float4*)(dst + i * 8) = v0;
            *(float4*)(dst + i * 8 + 4) = v1;
        }
    }
}

// ---------------------------------------------------------------------------
extern "C" void kernel_launch(void* const* d_in, const int* in_sizes, int n_in,
                              void* d_out, int out_size, void* d_ws, size_t ws_size,
                              hipStream_t stream) {
    const float* obs  = (const float*)d_in[0];
    const float* W1   = (const float*)d_in[1];
    const float* b1   = (const float*)d_in[2];
    const float* gg1  = (const float*)d_in[3];
    const float* be1  = (const float*)d_in[4];
    const float* W2   = (const float*)d_in[5];
    const float* b2   = (const float*)d_in[6];
    const float* gg2  = (const float*)d_in[7];
    const float* be2  = (const float*)d_in[8];
    const float* Wa1  = (const float*)d_in[9];
    const float* ba1  = (const float*)d_in[10];
    const float* Wa2  = (const float*)d_in[11];
    const float* ba2  = (const float*)d_in[12];
    const float* Wa3  = (const float*)d_in[13];
    const float* ba3  = (const float*)d_in[14];
    const float* Wf_ih = (const float*)d_in[15];
    const float* Wf_hh = (const float*)d_in[16];
    const float* bf_ih = (const float*)d_in[17];
    const float* bf_hh = (const float*)d_in[18];
    const float* Wb_ih = (const float*)d_in[19];
    const float* Wb_hh = (const float*)d_in[20];
    const float* bb_ih = (const float*)d_in[21];
    const float* bb_hh = (const float*)d_in[22];
    const float* W3   = (const float*)d_in[23];
    const float* b3   = (const float*)d_in[24];
    const float* gg3  = (const float*)d_in[25];
    const float* be3  = (const float*)d_in[26];
    const float* W4   = (const float*)d_in[27];
    const float* b4   = (const float*)d_in[28];
    const float* gg4  = (const float*)d_in[29];
    const float* be4  = (const float*)d_in[30];

    float* out     = (float*)d_out;
    float* out_acts = out;                   // 128*128*64
    float* out_C    = out + 1048576;         // 128*128*128
    float* out_ip   = out + 3145728;         // 16384
    float* out_ii   = out + 3162112;         // 16384
    float* out_nt   = out + 3178496;         // 128*128*256 (evolving thoughts)
    float* out_ot   = out + 7372800;         // 128*128*256 (old thoughts)

    float* ws    = (float*)d_ws;
    float* h1    = ws;                               // 4194304
    float* abuf  = ws + 4194304;                     // 2097152 (a1, later dot)
    float* a2buf = ws + 6291456;                     // 2097152 (a2, later act-pre)
    unsigned short* wihbf = (unsigned short*)(ws + 8388608);  // 262144 shorts
    float* biasz = ws + 8519680;                     // 1024
    unsigned short* whhbf = (unsigned short*)(ws + 8520704);  // 131072 shorts
    float* sqb   = ws + 8586240;                     // 16384
    int* idxb    = (int*)(ws + 8602624);             // 262144
    int* flagsb  = (int*)(ws + 8864768);             // 16384

    prep_kernel<<<512, 256, 0, stream>>>(Wf_ih, Wb_ih, Wf_hh, Wb_hh,
                                         bf_ih, bf_hh, bb_ih, bb_hh,
                                         wihbf, whhbf, biasz);

    // actor_1
    gemm64<<<dim3(4, 256), 256, 0, stream>>>(obs, W1, b1, h1, 16384, 256, 512, 0);
    ln256_kernel<<<4096, 256, 0, stream>>>(h1, h1, nullptr, gg1, be1, 1);
    gemm64<<<dim3(4, 256), 256, 0, stream>>>(h1, W2, b2, out_nt, 16384, 256, 256, 0);
    ln256_kernel<<<4096, 256, 0, stream>>>(out_nt, out_nt, out_ot, gg2, be2, 0);

    // attention unit
    gemm64<<<dim3(2, 256), 256, 0, stream>>>(out_nt, Wa1, ba1, abuf, 16384, 128, 256, 1);
    gemm64<<<dim3(2, 256), 256, 0, stream>>>(abuf, Wa2, ba2, a2buf, 16384, 128, 128, 1);
    attn_head_kernel<<<4096, 256, 0, stream>>>(a2buf, Wa3, ba3, out_ip, out_ii, flagsb);

    // pairwise distances + top-16
    dot_kernel<<<256, 256, 0, stream>>>(out_nt, abuf);
    sq_kernel<<<64, 256, 0, stream>>>(abuf, sqb);
    topk_kernel<<<4096, 256, 0, stream>>>(abuf, sqb, flagsb, out_C, idxb);

    // sequential communication chain (mutates out_nt), all-LDS agent loop
    chain_kernel<<<128, 512, 0, stream>>>(out_nt, whhbf, wihbf, biasz, idxb, flagsb);

    // actor_2
    gemm64<<<dim3(4, 256), 256, 0, stream>>>(out_nt, W3, b3, h1, 16384, 256, 256, 2);
    ln256_kernel<<<4096, 256, 0, stream>>>(h1, h1, nullptr, gg3, be3, 0);
    gemm64<<<dim3(1, 256), 256, 0, stream>>>(h1, W4, b4, a2buf, 16384, 64, 256, 0);
    ln64_tanh_kernel<<<4096, 256, 0, stream>>>(a2buf, out_acts, gg4, be4);
}